// Round 1
// baseline (845.325 us; speedup 1.0000x reference)
//
#include <hip/hip_runtime.h>

#define NSRC 20000
#define NTGT 20000
#define NEDGE 320000
#define COORD_MAX 10.0f

#define TILE_E 64
#define LDIN 296   // ushort stride for edge_in tile (K padded to 288, +8 pad; 592B, 16B-aligned)
#define LDH  136   // ushort stride for h/e tiles (272B, 16B-aligned)

#define TILE_N 64
#define LDN  264   // ushort stride for node input tile (K=256, 528B, 16B-aligned)

typedef __attribute__((ext_vector_type(4))) float f32x4;
typedef __attribute__((ext_vector_type(8))) short short8;
typedef __attribute__((ext_vector_type(8))) __bf16 bf16x8;

static __device__ __forceinline__ f32x4 mfma16(short8 a, short8 b, f32x4 c) {
  return __builtin_amdgcn_mfma_f32_16x16x32_bf16(
      __builtin_bit_cast(bf16x8, a), __builtin_bit_cast(bf16x8, b), c, 0, 0, 0);
}

static __device__ __forceinline__ unsigned short f2bf(float f) {
  unsigned u = __builtin_bit_cast(unsigned, f);
  u += 0x7FFFu + ((u >> 16) & 1u);   // round-to-nearest-even (no NaNs in this workload)
  return (unsigned short)(u >> 16);
}
static __device__ __forceinline__ float sigm(float x) { return 1.f / (1.f + __expf(-x)); }
static __device__ __forceinline__ float silu_(float x) { return x * sigm(x); }

// ---------------------------------------------------------------------------
// Pack fp32 weight [Kreal][128] (row-major) into MFMA B-fragment order (bf16):
// frag (kstep, ct): lane l holds 8 elems k = kstep*32 + (l>>4)*8 + j, col = ct*16 + (l&15).
// out index = ((kstep*8 + ct)*64 + lane)*8 + j.  Rows k >= Kreal are zero-padded.
// ---------------------------------------------------------------------------
__global__ void egnn_pack(const float* __restrict__ w, unsigned short* __restrict__ out,
                          int Kreal, int ksteps) {
  int idx = blockIdx.x * 256 + threadIdx.x;
  int total = ksteps * 512;           // ksteps * 8 * 64
  if (idx >= total) return;
  int lane  = idx & 63;
  int ct    = (idx >> 6) & 7;
  int kstep = idx >> 9;
  int col = ct * 16 + (lane & 15);
  int k0  = kstep * 32 + (lane >> 4) * 8;
  union { short8 s; unsigned short u[8]; } tmp;
#pragma unroll
  for (int j = 0; j < 8; ++j) {
    int k = k0 + j;
    tmp.u[j] = (k < Kreal) ? f2bf(w[(size_t)k * 128 + col]) : (unsigned short)0;
  }
  *(reinterpret_cast<short8*>(out) + idx) = tmp.s;
}

// ---------------------------------------------------------------------------
// Fused edge kernel: 64 edges per block (4 waves x 16 edges).
// Per direction: GEMM1(K=288) -> SiLU -> GEMM2(K=128) -> SiLU -> gate,
// then (s2t only) coord MLP, then atomic scatter into agg buffers.
// ---------------------------------------------------------------------------
__global__ __launch_bounds__(256, 2) void egnn_edge(
    const float* __restrict__ srcF, const float* __restrict__ tgtF,
    const float* __restrict__ srcC, const float* __restrict__ tgtC,
    const int* __restrict__ eSrc, const int* __restrict__ eTgt,
    const unsigned short* __restrict__ w1pA, const float* __restrict__ b1A,
    const unsigned short* __restrict__ w2pA, const float* __restrict__ b2A,
    const float* __restrict__ wgA, const float* __restrict__ bgA,
    const unsigned short* __restrict__ w1pB, const float* __restrict__ b1B,
    const unsigned short* __restrict__ w2pB, const float* __restrict__ b2B,
    const float* __restrict__ wgB, const float* __restrict__ bgB,
    const unsigned short* __restrict__ wc1p, const float* __restrict__ bc1,
    const float* __restrict__ wc2,
    float* __restrict__ aggA /*[NTGT][128] by tgt*/,
    float* __restrict__ aggB /*[NSRC][128] by src*/,
    float* __restrict__ trans /*[NTGT][3]*/, float* __restrict__ cntv /*[NTGT]*/)
{
  __shared__ __align__(16) unsigned short sIn[TILE_E * LDIN];
  __shared__ __align__(16) unsigned short sH[TILE_E * LDH];
  __shared__ float sCD[TILE_E * 3];

  const int tid = threadIdx.x;
  const int e0 = blockIdx.x * TILE_E;

  // ---- build edge_in tile (bf16): [src 0..127 | tgt 128..255 | radial 256 | zeros..287]
  {
    const int g = tid >> 5;       // 0..7, 32-lane groups
    const int l32 = tid & 31;
    for (int ri = g; ri < TILE_E * 2; ri += 8) {
      const int le = ri >> 1;
      const int which = ri & 1;   // 0 = src feat, 1 = tgt feat
      const int node = which ? eTgt[e0 + le] : eSrc[e0 + le];
      const float4 v = reinterpret_cast<const float4*>(
          (which ? tgtF : srcF) + (size_t)node * 128)[l32];
      ushort4 b;
      b.x = f2bf(v.x); b.y = f2bf(v.y); b.z = f2bf(v.z); b.w = f2bf(v.w);
      *reinterpret_cast<ushort4*>(&sIn[le * LDIN + which * 128 + l32 * 4]) = b;
    }
    if (tid < TILE_E) {
      const int le = tid;
      const int s = eSrc[e0 + le], t = eTgt[e0 + le];
      const float dx = tgtC[t * 3 + 0] - srcC[s * 3 + 0];
      const float dy = tgtC[t * 3 + 1] - srcC[s * 3 + 1];
      const float dz = tgtC[t * 3 + 2] - srcC[s * 3 + 2];
      sCD[le * 3 + 0] = dx; sCD[le * 3 + 1] = dy; sCD[le * 3 + 2] = dz;
      sIn[le * LDIN + 256] = f2bf(dx * dx + dy * dy + dz * dz);
      for (int c = 257; c < 288; ++c) sIn[le * LDIN + c] = 0;
    }
  }
  __syncthreads();

  const int lane = tid & 63;
  const int wid = tid >> 6;          // 0..3
  const int rowBase = wid * 16;      // this wave's 16 edges (local rows)
  const int r16 = lane & 15;
  const int g4 = lane >> 4;          // 0..3

  for (int dir = 0; dir < 2; ++dir) {
    const unsigned short* w1p = dir ? w1pB : w1pA;
    const float* b1 = dir ? b1B : b1A;
    const unsigned short* w2p = dir ? w2pB : w2pA;
    const float* b2 = dir ? b2B : b2A;
    const float* wg = dir ? wgB : wgA;
    const float bg = dir ? bgB[0] : bgA[0];
    const int* idxp = dir ? eSrc : eTgt;   // scatter index: s2t->tgt, t2s->src
    float* agg = dir ? aggB : aggA;

    // ---- GEMM1: [16 x 288] @ [288 x 128]
    f32x4 acc[8];
#pragma unroll
    for (int ct = 0; ct < 8; ++ct) acc[ct] = f32x4{0.f, 0.f, 0.f, 0.f};
#pragma unroll
    for (int ks = 0; ks < 9; ++ks) {
      const short8 a = *reinterpret_cast<const short8*>(
          &sIn[(rowBase + r16) * LDIN + ks * 32 + g4 * 8]);
#pragma unroll
      for (int ct = 0; ct < 8; ++ct) {
        const short8 b = *reinterpret_cast<const short8*>(
            w1p + ((size_t)(ks * 8 + ct) * 64 + lane) * 8);
        acc[ct] = mfma16(a, b, acc[ct]);
      }
    }
    // bias + SiLU -> sH (bf16)
#pragma unroll
    for (int ct = 0; ct < 8; ++ct) {
      const int col = ct * 16 + r16;
      const float bias = b1[col];
#pragma unroll
      for (int r = 0; r < 4; ++r) {
        const float h = silu_(acc[ct][r] + bias);
        sH[(rowBase + g4 * 4 + r) * LDH + col] = f2bf(h);
      }
    }

    // ---- GEMM2: [16 x 128] @ [128 x 128]
    f32x4 acc2[8];
#pragma unroll
    for (int ct = 0; ct < 8; ++ct) acc2[ct] = f32x4{0.f, 0.f, 0.f, 0.f};
#pragma unroll
    for (int ks = 0; ks < 4; ++ks) {
      const short8 a = *reinterpret_cast<const short8*>(
          &sH[(rowBase + r16) * LDH + ks * 32 + g4 * 8]);
#pragma unroll
      for (int ct = 0; ct < 8; ++ct) {
        const short8 b = *reinterpret_cast<const short8*>(
            w2p + ((size_t)(ks * 8 + ct) * 64 + lane) * 8);
        acc2[ct] = mfma16(a, b, acc2[ct]);
      }
    }

    // bias + SiLU + gate dot (e . wg), 16-lane reduce
    float part[4] = {0.f, 0.f, 0.f, 0.f};
#pragma unroll
    for (int ct = 0; ct < 8; ++ct) {
      const int col = ct * 16 + r16;
      const float bias = b2[col];
      const float wgv = wg[col];
#pragma unroll
      for (int r = 0; r < 4; ++r) {
        const float e = silu_(acc2[ct][r] + bias);
        acc2[ct][r] = e;
        part[r] += e * wgv;
      }
    }
#pragma unroll
    for (int m = 1; m < 16; m <<= 1)
#pragma unroll
      for (int r = 0; r < 4; ++r) part[r] += __shfl_xor(part[r], m, 64);
    float gate[4];
#pragma unroll
    for (int r = 0; r < 4; ++r) gate[r] = sigm(part[r] + bg);
#pragma unroll
    for (int ct = 0; ct < 8; ++ct)
#pragma unroll
      for (int r = 0; r < 4; ++r) acc2[ct][r] *= gate[r];

    int nidx[4];
#pragma unroll
    for (int r = 0; r < 4; ++r) nidx[r] = idxp[e0 + rowBase + g4 * 4 + r];

    if (dir == 0) {
      // gated e_s2t (bf16) -> sH for coord MLP
#pragma unroll
      for (int ct = 0; ct < 8; ++ct) {
        const int col = ct * 16 + r16;
#pragma unroll
        for (int r = 0; r < 4; ++r)
          sH[(rowBase + g4 * 4 + r) * LDH + col] = f2bf(acc2[ct][r]);
      }
      // coord GEMM: [16 x 128] @ [128 x 128]
      f32x4 acc3[8];
#pragma unroll
      for (int ct = 0; ct < 8; ++ct) acc3[ct] = f32x4{0.f, 0.f, 0.f, 0.f};
#pragma unroll
      for (int ks = 0; ks < 4; ++ks) {
        const short8 a = *reinterpret_cast<const short8*>(
            &sH[(rowBase + r16) * LDH + ks * 32 + g4 * 8]);
#pragma unroll
        for (int ct = 0; ct < 8; ++ct) {
          const short8 b = *reinterpret_cast<const short8*>(
              wc1p + ((size_t)(ks * 8 + ct) * 64 + lane) * 8);
          acc3[ct] = mfma16(a, b, acc3[ct]);
        }
      }
      float pc[4] = {0.f, 0.f, 0.f, 0.f};
#pragma unroll
      for (int ct = 0; ct < 8; ++ct) {
        const int col = ct * 16 + r16;
        const float bcv = bc1[col];
        const float w2v = wc2[col];
#pragma unroll
        for (int r = 0; r < 4; ++r) {
          const float c = silu_(acc3[ct][r] + bcv);
          pc[r] += c * w2v;
        }
      }
#pragma unroll
      for (int m = 1; m < 16; m <<= 1)
#pragma unroll
        for (int r = 0; r < 4; ++r) pc[r] += __shfl_xor(pc[r], m, 64);

      // scatter weighted coord_diff + counts (lanes 0..3 of each 16-group)
#pragma unroll
      for (int r = 0; r < 4; ++r) {
        const int row = rowBase + g4 * 4 + r;
        if (r16 < 3)
          atomicAdd(&trans[(size_t)nidx[r] * 3 + r16], sCD[row * 3 + r16] * pc[r]);
        else if (r16 == 3)
          atomicAdd(&cntv[nidx[r]], 1.0f);
      }
    }

    // ---- scatter gated e into agg
#pragma unroll
    for (int ct = 0; ct < 8; ++ct) {
      const int col = ct * 16 + r16;
#pragma unroll
      for (int r = 0; r < 4; ++r)
        atomicAdd(&agg[(size_t)nidx[r] * 128 + col], acc2[ct][r]);
    }
  }
}

// ---------------------------------------------------------------------------
// Node kernel: out = feat + (silu([feat|agg] @ wn1 + bn1) @ wn2 + bn2)
// 64 nodes per block (4 waves x 16).
// ---------------------------------------------------------------------------
__global__ __launch_bounds__(256, 2) void egnn_node(
    const float* __restrict__ feat, const float* __restrict__ agg,
    const unsigned short* __restrict__ w1p, const float* __restrict__ b1,
    const unsigned short* __restrict__ w2p, const float* __restrict__ b2,
    float* __restrict__ outp, int N)
{
  __shared__ __align__(16) unsigned short sIn[TILE_N * LDN];
  __shared__ __align__(16) unsigned short sH[TILE_N * LDH];
  const int tid = threadIdx.x;
  const int n0 = blockIdx.x * TILE_N;

  {
    const int g = tid >> 5;
    const int l32 = tid & 31;
    for (int ri = g; ri < TILE_N * 2; ri += 8) {
      const int ln = ri >> 1;
      const int which = ri & 1;   // 0 = feat, 1 = agg
      const int node = n0 + ln;
      float4 v = {0.f, 0.f, 0.f, 0.f};
      if (node < N)
        v = reinterpret_cast<const float4*>((which ? agg : feat) + (size_t)node * 128)[l32];
      ushort4 b;
      b.x = f2bf(v.x); b.y = f2bf(v.y); b.z = f2bf(v.z); b.w = f2bf(v.w);
      *reinterpret_cast<ushort4*>(&sIn[ln * LDN + which * 128 + l32 * 4]) = b;
    }
  }
  __syncthreads();

  const int lane = tid & 63;
  const int wid = tid >> 6;
  const int rowBase = wid * 16;
  const int r16 = lane & 15;
  const int g4 = lane >> 4;

  f32x4 acc[8];
#pragma unroll
  for (int ct = 0; ct < 8; ++ct) acc[ct] = f32x4{0.f, 0.f, 0.f, 0.f};
#pragma unroll
  for (int ks = 0; ks < 8; ++ks) {
    const short8 a = *reinterpret_cast<const short8*>(
        &sIn[(rowBase + r16) * LDN + ks * 32 + g4 * 8]);
#pragma unroll
    for (int ct = 0; ct < 8; ++ct) {
      const short8 b = *reinterpret_cast<const short8*>(
          w1p + ((size_t)(ks * 8 + ct) * 64 + lane) * 8);
      acc[ct] = mfma16(a, b, acc[ct]);
    }
  }
#pragma unroll
  for (int ct = 0; ct < 8; ++ct) {
    const int col = ct * 16 + r16;
    const float bias = b1[col];
#pragma unroll
    for (int r = 0; r < 4; ++r) {
      const float h = silu_(acc[ct][r] + bias);
      sH[(rowBase + g4 * 4 + r) * LDH + col] = f2bf(h);
    }
  }

  f32x4 acc2[8];
#pragma unroll
  for (int ct = 0; ct < 8; ++ct) acc2[ct] = f32x4{0.f, 0.f, 0.f, 0.f};
#pragma unroll
  for (int ks = 0; ks < 4; ++ks) {
    const short8 a = *reinterpret_cast<const short8*>(
        &sH[(rowBase + r16) * LDH + ks * 32 + g4 * 8]);
#pragma unroll
    for (int ct = 0; ct < 8; ++ct) {
      const short8 b = *reinterpret_cast<const short8*>(
          w2p + ((size_t)(ks * 8 + ct) * 64 + lane) * 8);
      acc2[ct] = mfma16(a, b, acc2[ct]);
    }
  }

#pragma unroll
  for (int ct = 0; ct < 8; ++ct) {
    const int col = ct * 16 + r16;
    const float bias = b2[col];
#pragma unroll
    for (int r = 0; r < 4; ++r) {
      const int node = n0 + rowBase + g4 * 4 + r;
      if (node < N)
        outp[(size_t)node * 128 + col] = feat[(size_t)node * 128 + col] + acc2[ct][r] + bias;
    }
  }
}

// ---------------------------------------------------------------------------
// Coord finalize: copy src coords; tgt_coord_out = tgt + clip(trans/max(cnt,1)).
// ---------------------------------------------------------------------------
__global__ void egnn_coord(const float* __restrict__ srcC, const float* __restrict__ tgtC,
                           const float* __restrict__ trans, const float* __restrict__ cntv,
                           float* __restrict__ outSC, float* __restrict__ outTC) {
  const int i = blockIdx.x * 256 + threadIdx.x;
  if (i >= NTGT * 3) return;
  outSC[i] = srcC[i];
  const int n = i / 3;
  const float c = fmaxf(cntv[n], 1.f);
  float a = trans[i] / c;
  a = fminf(fmaxf(a, -COORD_MAX), COORD_MAX);
  outTC[i] = tgtC[i] + a;
}

extern "C" void kernel_launch(void* const* d_in, const int* in_sizes, int n_in,
                              void* d_out, int out_size, void* d_ws, size_t ws_size,
                              hipStream_t stream) {
  const float* srcF = (const float*)d_in[0];
  const float* tgtF = (const float*)d_in[1];
  const float* srcC = (const float*)d_in[2];
  const float* tgtC = (const float*)d_in[3];
  const int* eSrc = (const int*)d_in[4];
  const int* eTgt = (const int*)d_in[5];
  const float* w1_s2t = (const float*)d_in[6];
  const float* b1_s2t = (const float*)d_in[7];
  const float* w2_s2t = (const float*)d_in[8];
  const float* b2_s2t = (const float*)d_in[9];
  const float* w1_t2s = (const float*)d_in[10];
  const float* b1_t2s = (const float*)d_in[11];
  const float* w2_t2s = (const float*)d_in[12];
  const float* b2_t2s = (const float*)d_in[13];
  const float* wg_s2t = (const float*)d_in[14];
  const float* bg_s2t = (const float*)d_in[15];
  const float* wg_t2s = (const float*)d_in[16];
  const float* bg_t2s = (const float*)d_in[17];
  const float* wc1 = (const float*)d_in[18];
  const float* bc1 = (const float*)d_in[19];
  const float* wc2 = (const float*)d_in[20];
  const float* wn1_t = (const float*)d_in[21];
  const float* bn1_t = (const float*)d_in[22];
  const float* wn2_t = (const float*)d_in[23];
  const float* bn2_t = (const float*)d_in[24];
  const float* wn1_s = (const float*)d_in[25];
  const float* bn1_s = (const float*)d_in[26];
  const float* wn2_s = (const float*)d_in[27];
  const float* bn2_s = (const float*)d_in[28];

  char* ws = (char*)d_ws;
  float* aggS2T = (float*)(ws + 0);           // NT*128 f32 = 10,240,000 B
  float* aggT2S = (float*)(ws + 10240000);    // NS*128 f32
  float* trans  = (float*)(ws + 20480000);    // NT*3  f32
  float* cntv   = (float*)(ws + 20720000);    // NT    f32
  unsigned short* w1p_s2t = (unsigned short*)(ws + 20800000);
  unsigned short* w1p_t2s = w1p_s2t + 9 * 4096;   // 36864 elems each
  unsigned short* w2p_s2t = w1p_t2s + 9 * 4096;
  unsigned short* w2p_t2s = w2p_s2t + 4 * 4096;
  unsigned short* wc1p    = w2p_t2s + 4 * 4096;
  unsigned short* wn1p_t  = wc1p    + 4 * 4096;
  unsigned short* wn2p_t  = wn1p_t  + 8 * 4096;
  unsigned short* wn1p_s  = wn2p_t  + 4 * 4096;
  unsigned short* wn2p_s  = wn1p_s  + 8 * 4096;

  // zero the atomic accumulators (agg + trans + cnt)
  hipMemsetAsync(ws, 0, 20800000, stream);

  // pack weights into MFMA fragment order (bf16)
  egnn_pack<<<18, 256, 0, stream>>>(w1_s2t, w1p_s2t, 257, 9);
  egnn_pack<<<18, 256, 0, stream>>>(w1_t2s, w1p_t2s, 257, 9);
  egnn_pack<<<8, 256, 0, stream>>>(w2_s2t, w2p_s2t, 128, 4);
  egnn_pack<<<8, 256, 0, stream>>>(w2_t2s, w2p_t2s, 128, 4);
  egnn_pack<<<8, 256, 0, stream>>>(wc1, wc1p, 128, 4);
  egnn_pack<<<16, 256, 0, stream>>>(wn1_t, wn1p_t, 256, 8);
  egnn_pack<<<8, 256, 0, stream>>>(wn2_t, wn2p_t, 128, 4);
  egnn_pack<<<16, 256, 0, stream>>>(wn1_s, wn1p_s, 256, 8);
  egnn_pack<<<8, 256, 0, stream>>>(wn2_s, wn2p_s, 128, 4);

  egnn_edge<<<NEDGE / TILE_E, 256, 0, stream>>>(
      srcF, tgtF, srcC, tgtC, eSrc, eTgt,
      w1p_s2t, b1_s2t, w2p_s2t, b2_s2t, wg_s2t, bg_s2t,
      w1p_t2s, b1_t2s, w2p_t2s, b2_t2s, wg_t2s, bg_t2s,
      wc1p, bc1, wc2,
      aggS2T, aggT2S, trans, cntv);

  float* outSrc = (float*)d_out;
  float* outTgt = outSrc + (size_t)NSRC * 128;
  float* outSC  = outTgt + (size_t)NTGT * 128;
  float* outTC  = outSC + (size_t)NSRC * 3;

  egnn_node<<<(NTGT + TILE_N - 1) / TILE_N, 256, 0, stream>>>(
      tgtF, aggS2T, wn1p_t, bn1_t, wn2p_t, bn2_t, outTgt, NTGT);
  egnn_node<<<(NSRC + TILE_N - 1) / TILE_N, 256, 0, stream>>>(
      srcF, aggT2S, wn1p_s, bn1_s, wn2p_s, bn2_s, outSrc, NSRC);

  egnn_coord<<<(NTGT * 3 + 255) / 256, 256, 0, stream>>>(
      srcC, tgtC, trans, cntv, outSC, outTC);
}

// Round 2
// 590.862 us; speedup vs baseline: 1.4307x; 1.4307x over previous
//
#include <hip/hip_runtime.h>

#define NSRC 20000
#define NTGT 20000
#define NEDGE 320000
#define COORD_MAX 10.0f

#define LDH 136    // ushort stride (272B, 16B-aligned, 68 words ≡ 4 mod 32 -> rotates banks)

#define TILE_N 64
#define LDN  264   // node kernel input stride (K=256)

typedef __attribute__((ext_vector_type(4))) float f32x4;
typedef __attribute__((ext_vector_type(8))) short short8;
typedef __attribute__((ext_vector_type(8))) __bf16 bf16x8;

static __device__ __forceinline__ f32x4 mfma16(short8 a, short8 b, f32x4 c) {
  return __builtin_amdgcn_mfma_f32_16x16x32_bf16(
      __builtin_bit_cast(bf16x8, a), __builtin_bit_cast(bf16x8, b), c, 0, 0, 0);
}
static __device__ __forceinline__ unsigned short f2bf(float f) {
  unsigned u = __builtin_bit_cast(unsigned, f);
  u += 0x7FFFu + ((u >> 16) & 1u);
  return (unsigned short)(u >> 16);
}
static __device__ __forceinline__ float bf2f(unsigned short u) {
  unsigned x = ((unsigned)u) << 16;
  return __builtin_bit_cast(float, x);
}
static __device__ __forceinline__ float sigm(float x) { return 1.f / (1.f + __expf(-x)); }
static __device__ __forceinline__ float silu_(float x) { return x * sigm(x); }

// ---------------------------------------------------------------------------
// Merged weight pack: fp32 [Kreal][128] row-major -> bf16 MFMA B-fragment order.
// frag (kstep, ct): lane l holds k = kstep*32 + (l>>4)*8 + j, col = ct*16 + (l&15).
// ---------------------------------------------------------------------------
struct PackJobs {
  const float* w[11];
  unsigned short* o[11];
  int kreal[11];
  int nk[11];
};

__global__ void egnn_pack_all(PackJobs J) {
  const int job = blockIdx.y;
  const int nk = J.nk[job];
  const int idx = blockIdx.x * 256 + threadIdx.x;
  if (idx >= nk * 512) return;
  const float* w = J.w[job];
  const int kreal = J.kreal[job];
  const int lane = idx & 63;
  const int ct = (idx >> 6) & 7;
  const int kstep = idx >> 9;
  const int col = ct * 16 + (lane & 15);
  const int k0 = kstep * 32 + (lane >> 4) * 8;
  union { short8 s; unsigned short u[8]; } t;
#pragma unroll
  for (int j = 0; j < 8; ++j) {
    int k = k0 + j;
    t.u[j] = (k < kreal) ? f2bf(w[(size_t)k * 128 + col]) : (unsigned short)0;
  }
  reinterpret_cast<short8*>(J.o[job])[idx] = t.s;
}

// ---------------------------------------------------------------------------
// Precompute S1/T1 = X @ W (K=128), output bf16 [N][128]. 4 jobs via blockIdx.y.
// ---------------------------------------------------------------------------
struct PreJobs {
  const float* x[4];
  const unsigned short* w[4];
  unsigned short* o[4];
};

__global__ __launch_bounds__(256, 2) void egnn_pre(PreJobs J, int N) {
  __shared__ __align__(16) unsigned short sX[64 * LDH];
  const int job = blockIdx.y;
  const float* X = J.x[job];
  const unsigned short* W = J.w[job];
  unsigned short* O = J.o[job];
  const int n0 = blockIdx.x * 64;
  const int tid = threadIdx.x;

  for (int s = tid; s < 64 * 32; s += 256) {
    const int row = s >> 5;
    const int c4 = (s & 31) * 4;
    const int node = n0 + row;
    float4 v = {0.f, 0.f, 0.f, 0.f};
    if (node < N) v = reinterpret_cast<const float4*>(X + (size_t)node * 128)[s & 31];
    ushort4 b = {f2bf(v.x), f2bf(v.y), f2bf(v.z), f2bf(v.w)};
    *reinterpret_cast<ushort4*>(&sX[row * LDH + c4]) = b;
  }
  __syncthreads();

  const int lane = tid & 63, wid = tid >> 6;
  const int r16 = lane & 15, g4 = lane >> 4;
  const int rowBase = wid * 16;

  f32x4 acc[8];
#pragma unroll
  for (int ct = 0; ct < 8; ++ct) acc[ct] = f32x4{0.f, 0.f, 0.f, 0.f};
#pragma unroll
  for (int ks = 0; ks < 4; ++ks) {
    const short8 a = *reinterpret_cast<const short8*>(
        &sX[(rowBase + r16) * LDH + ks * 32 + g4 * 8]);
#pragma unroll
    for (int ct = 0; ct < 8; ++ct) {
      const short8 b = *reinterpret_cast<const short8*>(
          W + ((size_t)(ks * 8 + ct) * 64 + lane) * 8);
      acc[ct] = mfma16(a, b, acc[ct]);
    }
  }
#pragma unroll
  for (int ct = 0; ct < 8; ++ct) {
    const int col = ct * 16 + r16;
#pragma unroll
    for (int r = 0; r < 4; ++r) {
      const int node = n0 + rowBase + g4 * 4 + r;
      if (node < N) O[(size_t)node * 128 + col] = f2bf(acc[ct][r]);
    }
  }
}

// ---------------------------------------------------------------------------
// Fused edge kernel. 256 edges/block, 4 waves x 64 edges (4 row-tiles each).
// h1 = silu(S1[es] + T1[et] + radial*w1_rad + b1)  (GEMM1 decomposed away)
// then GEMM2 -> gate -> scatter; dir0 additionally coord-MLP -> coord scatter.
// ---------------------------------------------------------------------------
__global__ __launch_bounds__(256, 2) void egnn_edge(
    const unsigned short* __restrict__ S1A, const unsigned short* __restrict__ T1A,
    const unsigned short* __restrict__ S1B, const unsigned short* __restrict__ T1B,
    const float* __restrict__ srcC, const float* __restrict__ tgtC,
    const int* __restrict__ eSrc, const int* __restrict__ eTgt,
    const float* __restrict__ w1A, const float* __restrict__ b1A,
    const float* __restrict__ w1B, const float* __restrict__ b1B,
    const unsigned short* __restrict__ w2pA, const float* __restrict__ b2A,
    const float* __restrict__ wgA, const float* __restrict__ bgA,
    const unsigned short* __restrict__ w2pB, const float* __restrict__ b2B,
    const float* __restrict__ wgB, const float* __restrict__ bgB,
    const unsigned short* __restrict__ wc1p, const float* __restrict__ bc1,
    const float* __restrict__ wc2,
    float* __restrict__ aggA, float* __restrict__ aggB,
    float* __restrict__ trans, float* __restrict__ cntv)
{
  __shared__ __align__(16) unsigned short sH[4][64 * LDH];  // 69632 B
  __shared__ float sCD[256 * 3];
  __shared__ float sRad[256];
  __shared__ int sS[256];
  __shared__ int sT[256];

  const int tid = threadIdx.x;
  const int e0 = blockIdx.x * 256;

  {
    const int e = e0 + tid;
    const int s = eSrc[e], t = eTgt[e];
    sS[tid] = s; sT[tid] = t;
    const float dx = tgtC[t * 3 + 0] - srcC[s * 3 + 0];
    const float dy = tgtC[t * 3 + 1] - srcC[s * 3 + 1];
    const float dz = tgtC[t * 3 + 2] - srcC[s * 3 + 2];
    sCD[tid * 3 + 0] = dx; sCD[tid * 3 + 1] = dy; sCD[tid * 3 + 2] = dz;
    sRad[tid] = dx * dx + dy * dy + dz * dz;
  }
  __syncthreads();

  const int lane = tid & 63, wid = tid >> 6;
  const int r16 = lane & 15, g4 = lane >> 4;
  const int we = wid * 64;
  const int h32 = lane >> 5;
  const int c4 = (lane & 31) * 4;

  // per-lane constants for the radial row + bias (4 cols each)
  const float4 radA = *reinterpret_cast<const float4*>(w1A + 256 * 128 + c4);
  const float4 biaA = *reinterpret_cast<const float4*>(b1A + c4);
  const float4 radB = *reinterpret_cast<const float4*>(w1B + 256 * 128 + c4);
  const float4 biaB = *reinterpret_cast<const float4*>(b1B + c4);

  unsigned short* hT = sH[wid];

  for (int dir = 0; dir < 2; ++dir) {
    const unsigned short* S1 = dir ? S1B : S1A;
    const unsigned short* T1 = dir ? T1B : T1A;
    const float4 wr = dir ? radB : radA;
    const float4 bb = dir ? biaB : biaA;

    // ---- build h-tile: h = silu(S1[s] + T1[t] + rad*wr + bb), bf16 -> LDS
#pragma unroll 8
    for (int i = 0; i < 32; ++i) {
      const int row = 2 * i + h32;
      const int e = we + row;
      const int s = sS[e], t = sT[e];
      const float rad = sRad[e];
      const ushort4 a = *reinterpret_cast<const ushort4*>(S1 + (size_t)s * 128 + c4);
      const ushort4 b = *reinterpret_cast<const ushort4*>(T1 + (size_t)t * 128 + c4);
      ushort4 o;
      o.x = f2bf(silu_(bf2f(a.x) + bf2f(b.x) + rad * wr.x + bb.x));
      o.y = f2bf(silu_(bf2f(a.y) + bf2f(b.y) + rad * wr.y + bb.y));
      o.z = f2bf(silu_(bf2f(a.z) + bf2f(b.z) + rad * wr.z + bb.z));
      o.w = f2bf(silu_(bf2f(a.w) + bf2f(b.w) + rad * wr.w + bb.w));
      *reinterpret_cast<ushort4*>(&hT[row * LDH + c4]) = o;
    }

    // ---- GEMM2: 4 row-tiles x [16x128] @ [128x128]; B frags reused over 4 rt
    const unsigned short* w2p = dir ? w2pB : w2pA;
    f32x4 acc[4][8];
#pragma unroll
    for (int rt = 0; rt < 4; ++rt)
#pragma unroll
      for (int ct = 0; ct < 8; ++ct) acc[rt][ct] = f32x4{0.f, 0.f, 0.f, 0.f};
#pragma unroll
    for (int ks = 0; ks < 4; ++ks) {
      short8 a[4];
#pragma unroll
      for (int rt = 0; rt < 4; ++rt)
        a[rt] = *reinterpret_cast<const short8*>(
            &hT[(rt * 16 + r16) * LDH + ks * 32 + g4 * 8]);
#pragma unroll
      for (int ct = 0; ct < 8; ++ct) {
        const short8 b = *reinterpret_cast<const short8*>(
            w2p + ((size_t)(ks * 8 + ct) * 64 + lane) * 8);
#pragma unroll
        for (int rt = 0; rt < 4; ++rt) acc[rt][ct] = mfma16(a[rt], b, acc[rt][ct]);
      }
    }

    // ---- bias + SiLU + gate
    const float* b2 = dir ? b2B : b2A;
    const float* wg = dir ? wgB : wgA;
    const float bg = dir ? bgB[0] : bgA[0];
    float part[4][4];
#pragma unroll
    for (int rt = 0; rt < 4; ++rt)
#pragma unroll
      for (int r = 0; r < 4; ++r) part[rt][r] = 0.f;
#pragma unroll
    for (int ct = 0; ct < 8; ++ct) {
      const float b2v = b2[ct * 16 + r16];
      const float wgv = wg[ct * 16 + r16];
#pragma unroll
      for (int rt = 0; rt < 4; ++rt)
#pragma unroll
        for (int r = 0; r < 4; ++r) {
          const float e = silu_(acc[rt][ct][r] + b2v);
          acc[rt][ct][r] = e;
          part[rt][r] += e * wgv;
        }
    }
#pragma unroll
    for (int m = 1; m < 16; m <<= 1)
#pragma unroll
      for (int rt = 0; rt < 4; ++rt)
#pragma unroll
        for (int r = 0; r < 4; ++r) part[rt][r] += __shfl_xor(part[rt][r], m, 64);
#pragma unroll
    for (int rt = 0; rt < 4; ++rt)
#pragma unroll
      for (int r = 0; r < 4; ++r) {
        const float gate = sigm(part[rt][r] + bg);
#pragma unroll
        for (int ct = 0; ct < 8; ++ct) acc[rt][ct][r] *= gate;
      }

    if (dir == 0) {
      // stash gated e_s2t (bf16) in LDS for the coord GEMM A operand
#pragma unroll
      for (int rt = 0; rt < 4; ++rt)
#pragma unroll
        for (int ct = 0; ct < 8; ++ct)
#pragma unroll
          for (int r = 0; r < 4; ++r)
            hT[(rt * 16 + g4 * 4 + r) * LDH + ct * 16 + r16] = f2bf(acc[rt][ct][r]);
    }

    // ---- atomic scatter into agg
    const int* loc = dir ? sS : sT;
    float* agg = dir ? aggB : aggA;
#pragma unroll
    for (int rt = 0; rt < 4; ++rt) {
      int nidx[4];
#pragma unroll
      for (int r = 0; r < 4; ++r) nidx[r] = loc[we + rt * 16 + g4 * 4 + r];
#pragma unroll
      for (int ct = 0; ct < 8; ++ct)
#pragma unroll
        for (int r = 0; r < 4; ++r)
          atomicAdd(&agg[(size_t)nidx[r] * 128 + ct * 16 + r16], acc[rt][ct][r]);
    }

    if (dir == 0) {
      // ---- coord GEMM on gated e_s2t
      f32x4 ac[4][8];
#pragma unroll
      for (int rt = 0; rt < 4; ++rt)
#pragma unroll
        for (int ct = 0; ct < 8; ++ct) ac[rt][ct] = f32x4{0.f, 0.f, 0.f, 0.f};
#pragma unroll
      for (int ks = 0; ks < 4; ++ks) {
        short8 a[4];
#pragma unroll
        for (int rt = 0; rt < 4; ++rt)
          a[rt] = *reinterpret_cast<const short8*>(
              &hT[(rt * 16 + r16) * LDH + ks * 32 + g4 * 8]);
#pragma unroll
        for (int ct = 0; ct < 8; ++ct) {
          const short8 b = *reinterpret_cast<const short8*>(
              wc1p + ((size_t)(ks * 8 + ct) * 64 + lane) * 8);
#pragma unroll
          for (int rt = 0; rt < 4; ++rt) ac[rt][ct] = mfma16(a[rt], b, ac[rt][ct]);
        }
      }
      float pc[4][4];
#pragma unroll
      for (int rt = 0; rt < 4; ++rt)
#pragma unroll
        for (int r = 0; r < 4; ++r) pc[rt][r] = 0.f;
#pragma unroll
      for (int ct = 0; ct < 8; ++ct) {
        const float bcv = bc1[ct * 16 + r16];
        const float w2v = wc2[ct * 16 + r16];
#pragma unroll
        for (int rt = 0; rt < 4; ++rt)
#pragma unroll
          for (int r = 0; r < 4; ++r)
            pc[rt][r] += silu_(ac[rt][ct][r] + bcv) * w2v;
      }
#pragma unroll
      for (int m = 1; m < 16; m <<= 1)
#pragma unroll
        for (int rt = 0; rt < 4; ++rt)
#pragma unroll
          for (int r = 0; r < 4; ++r) pc[rt][r] += __shfl_xor(pc[rt][r], m, 64);

#pragma unroll
      for (int rt = 0; rt < 4; ++rt)
#pragma unroll
        for (int r = 0; r < 4; ++r) {
          const int e = we + rt * 16 + g4 * 4 + r;
          const int n = sT[e];
          if (r16 < 3)
            atomicAdd(&trans[(size_t)n * 3 + r16], sCD[e * 3 + r16] * pc[rt][r]);
          else if (r16 == 3)
            atomicAdd(&cntv[n], 1.0f);
        }
    }
  }
}

// ---------------------------------------------------------------------------
// Node kernel: out = feat + (silu([feat|agg] @ wn1 + bn1) @ wn2 + bn2)
// ---------------------------------------------------------------------------
__global__ __launch_bounds__(256, 2) void egnn_node(
    const float* __restrict__ feat, const float* __restrict__ agg,
    const unsigned short* __restrict__ w1p, const float* __restrict__ b1,
    const unsigned short* __restrict__ w2p, const float* __restrict__ b2,
    float* __restrict__ outp, int N)
{
  __shared__ __align__(16) unsigned short sIn[TILE_N * LDN];
  __shared__ __align__(16) unsigned short sH2[TILE_N * LDH];
  const int tid = threadIdx.x;
  const int n0 = blockIdx.x * TILE_N;

  {
    const int g = tid >> 5;
    const int l32 = tid & 31;
    for (int ri = g; ri < TILE_N * 2; ri += 8) {
      const int ln = ri >> 1;
      const int which = ri & 1;
      const int node = n0 + ln;
      float4 v = {0.f, 0.f, 0.f, 0.f};
      if (node < N)
        v = reinterpret_cast<const float4*>((which ? agg : feat) + (size_t)node * 128)[l32];
      ushort4 b;
      b.x = f2bf(v.x); b.y = f2bf(v.y); b.z = f2bf(v.z); b.w = f2bf(v.w);
      *reinterpret_cast<ushort4*>(&sIn[ln * LDN + which * 128 + l32 * 4]) = b;
    }
  }
  __syncthreads();

  const int lane = tid & 63;
  const int wid = tid >> 6;
  const int rowBase = wid * 16;
  const int r16 = lane & 15;
  const int g4 = lane >> 4;

  f32x4 acc[8];
#pragma unroll
  for (int ct = 0; ct < 8; ++ct) acc[ct] = f32x4{0.f, 0.f, 0.f, 0.f};
#pragma unroll
  for (int ks = 0; ks < 8; ++ks) {
    const short8 a = *reinterpret_cast<const short8*>(
        &sIn[(rowBase + r16) * LDN + ks * 32 + g4 * 8]);
#pragma unroll
    for (int ct = 0; ct < 8; ++ct) {
      const short8 b = *reinterpret_cast<const short8*>(
          w1p + ((size_t)(ks * 8 + ct) * 64 + lane) * 8);
      acc[ct] = mfma16(a, b, acc[ct]);
    }
  }
#pragma unroll
  for (int ct = 0; ct < 8; ++ct) {
    const int col = ct * 16 + r16;
    const float bias = b1[col];
#pragma unroll
    for (int r = 0; r < 4; ++r) {
      const float h = silu_(acc[ct][r] + bias);
      sH2[(rowBase + g4 * 4 + r) * LDH + col] = f2bf(h);
    }
  }

  f32x4 acc2[8];
#pragma unroll
  for (int ct = 0; ct < 8; ++ct) acc2[ct] = f32x4{0.f, 0.f, 0.f, 0.f};
#pragma unroll
  for (int ks = 0; ks < 4; ++ks) {
    const short8 a = *reinterpret_cast<const short8*>(
        &sH2[(rowBase + r16) * LDH + ks * 32 + g4 * 8]);
#pragma unroll
    for (int ct = 0; ct < 8; ++ct) {
      const short8 b = *reinterpret_cast<const short8*>(
          w2p + ((size_t)(ks * 8 + ct) * 64 + lane) * 8);
      acc2[ct] = mfma16(a, b, acc2[ct]);
    }
  }

#pragma unroll
  for (int ct = 0; ct < 8; ++ct) {
    const int col = ct * 16 + r16;
    const float bias = b2[col];
#pragma unroll
    for (int r = 0; r < 4; ++r) {
      const int node = n0 + rowBase + g4 * 4 + r;
      if (node < N)
        outp[(size_t)node * 128 + col] = feat[(size_t)node * 128 + col] + acc2[ct][r] + bias;
    }
  }
}

__global__ void egnn_coord(const float* __restrict__ srcC, const float* __restrict__ tgtC,
                           const float* __restrict__ trans, const float* __restrict__ cntv,
                           float* __restrict__ outSC, float* __restrict__ outTC) {
  const int i = blockIdx.x * 256 + threadIdx.x;
  if (i >= NTGT * 3) return;
  outSC[i] = srcC[i];
  const int n = i / 3;
  const float c = fmaxf(cntv[n], 1.f);
  float a = trans[i] / c;
  a = fminf(fmaxf(a, -COORD_MAX), COORD_MAX);
  outTC[i] = tgtC[i] + a;
}

extern "C" void kernel_launch(void* const* d_in, const int* in_sizes, int n_in,
                              void* d_out, int out_size, void* d_ws, size_t ws_size,
                              hipStream_t stream) {
  const float* srcF = (const float*)d_in[0];
  const float* tgtF = (const float*)d_in[1];
  const float* srcC = (const float*)d_in[2];
  const float* tgtC = (const float*)d_in[3];
  const int* eSrc = (const int*)d_in[4];
  const int* eTgt = (const int*)d_in[5];
  const float* w1_s2t = (const float*)d_in[6];
  const float* b1_s2t = (const float*)d_in[7];
  const float* w2_s2t = (const float*)d_in[8];
  const float* b2_s2t = (const float*)d_in[9];
  const float* w1_t2s = (const float*)d_in[10];
  const float* b1_t2s = (const float*)d_in[11];
  const float* w2_t2s = (const float*)d_in[12];
  const float* b2_t2s = (const float*)d_in[13];
  const float* wg_s2t = (const float*)d_in[14];
  const float* bg_s2t = (const float*)d_in[15];
  const float* wg_t2s = (const float*)d_in[16];
  const float* bg_t2s = (const float*)d_in[17];
  const float* wc1 = (const float*)d_in[18];
  const float* bc1 = (const float*)d_in[19];
  const float* wc2 = (const float*)d_in[20];
  const float* wn1_t = (const float*)d_in[21];
  const float* bn1_t = (const float*)d_in[22];
  const float* wn2_t = (const float*)d_in[23];
  const float* bn2_t = (const float*)d_in[24];
  const float* wn1_s = (const float*)d_in[25];
  const float* bn1_s = (const float*)d_in[26];
  const float* wn2_s = (const float*)d_in[27];
  const float* bn2_s = (const float*)d_in[28];

  char* ws = (char*)d_ws;
  size_t off = 0;
  float* aggA = (float*)(ws + off); off += (size_t)NTGT * 128 * 4;   // by tgt
  float* aggB = (float*)(ws + off); off += (size_t)NSRC * 128 * 4;   // by src
  float* trans = (float*)(ws + off); off += (size_t)NTGT * 3 * 4;
  float* cntv = (float*)(ws + off); off += (size_t)NTGT * 4;
  const size_t zero_bytes = off;
  unsigned short* S1A = (unsigned short*)(ws + off); off += (size_t)NSRC * 128 * 2;
  unsigned short* T1A = (unsigned short*)(ws + off); off += (size_t)NTGT * 128 * 2;
  unsigned short* S1B = (unsigned short*)(ws + off); off += (size_t)NSRC * 128 * 2;
  unsigned short* T1B = (unsigned short*)(ws + off); off += (size_t)NTGT * 128 * 2;
  unsigned short* w1tA = (unsigned short*)(ws + off); off += 4 * 4096 * 2;
  unsigned short* w1mA = (unsigned short*)(ws + off); off += 4 * 4096 * 2;
  unsigned short* w1tB = (unsigned short*)(ws + off); off += 4 * 4096 * 2;
  unsigned short* w1mB = (unsigned short*)(ws + off); off += 4 * 4096 * 2;
  unsigned short* w2pA = (unsigned short*)(ws + off); off += 4 * 4096 * 2;
  unsigned short* w2pB = (unsigned short*)(ws + off); off += 4 * 4096 * 2;
  unsigned short* wc1p = (unsigned short*)(ws + off); off += 4 * 4096 * 2;
  unsigned short* wn1pt = (unsigned short*)(ws + off); off += 8 * 4096 * 2;
  unsigned short* wn2pt = (unsigned short*)(ws + off); off += 4 * 4096 * 2;
  unsigned short* wn1ps = (unsigned short*)(ws + off); off += 8 * 4096 * 2;
  unsigned short* wn2ps = (unsigned short*)(ws + off); off += 4 * 4096 * 2;

  hipMemsetAsync(ws, 0, zero_bytes, stream);

  PackJobs PJ;
  PJ.w[0] = w1_s2t;             PJ.o[0] = w1tA;  PJ.kreal[0] = 128; PJ.nk[0] = 4;
  PJ.w[1] = w1_s2t + 128 * 128; PJ.o[1] = w1mA;  PJ.kreal[1] = 128; PJ.nk[1] = 4;
  PJ.w[2] = w1_t2s;             PJ.o[2] = w1tB;  PJ.kreal[2] = 128; PJ.nk[2] = 4;
  PJ.w[3] = w1_t2s + 128 * 128; PJ.o[3] = w1mB;  PJ.kreal[3] = 128; PJ.nk[3] = 4;
  PJ.w[4] = w2_s2t;             PJ.o[4] = w2pA;  PJ.kreal[4] = 128; PJ.nk[4] = 4;
  PJ.w[5] = w2_t2s;             PJ.o[5] = w2pB;  PJ.kreal[5] = 128; PJ.nk[5] = 4;
  PJ.w[6] = wc1;                PJ.o[6] = wc1p;  PJ.kreal[6] = 128; PJ.nk[6] = 4;
  PJ.w[7] = wn1_t;              PJ.o[7] = wn1pt; PJ.kreal[7] = 256; PJ.nk[7] = 8;
  PJ.w[8] = wn2_t;              PJ.o[8] = wn2pt; PJ.kreal[8] = 128; PJ.nk[8] = 4;
  PJ.w[9] = wn1_s;              PJ.o[9] = wn1ps; PJ.kreal[9] = 256; PJ.nk[9] = 8;
  PJ.w[10] = wn2_s;             PJ.o[10] = wn2ps; PJ.kreal[10] = 128; PJ.nk[10] = 4;
  egnn_pack_all<<<dim3(16, 11), 256, 0, stream>>>(PJ);

  PreJobs PR;
  PR.x[0] = srcF; PR.w[0] = w1tA; PR.o[0] = S1A;
  PR.x[1] = tgtF; PR.w[1] = w1mA; PR.o[1] = T1A;
  PR.x[2] = srcF; PR.w[2] = w1tB; PR.o[2] = S1B;
  PR.x[3] = tgtF; PR.w[3] = w1mB; PR.o[3] = T1B;
  egnn_pre<<<dim3(313, 4), 256, 0, stream>>>(PR, NSRC);

  egnn_edge<<<NEDGE / 256, 256, 0, stream>>>(
      S1A, T1A, S1B, T1B, srcC, tgtC, eSrc, eTgt,
      w1_s2t, b1_s2t, w1_t2s, b1_t2s,
      w2pA, b2_s2t, wg_s2t, bg_s2t,
      w2pB, b2_t2s, wg_t2s, bg_t2s,
      wc1p, bc1, wc2,
      aggA, aggB, trans, cntv);

  float* outSrc = (float*)d_out;
  float* outTgt = outSrc + (size_t)NSRC * 128;
  float* outSC  = outTgt + (size_t)NTGT * 128;
  float* outTC  = outSC + (size_t)NSRC * 3;

  egnn_node<<<(NTGT + TILE_N - 1) / TILE_N, 256, 0, stream>>>(
      tgtF, aggA, wn1pt, bn1_t, wn2pt, bn2_t, outTgt, NTGT);
  egnn_node<<<(NSRC + TILE_N - 1) / TILE_N, 256, 0, stream>>>(
      srcF, aggB, wn1ps, bn1_s, wn2ps, bn2_s, outSrc, NSRC);

  egnn_coord<<<(NTGT * 3 + 255) / 256, 256, 0, stream>>>(
      srcC, tgtC, trans, cntv, outSC, outTC);
}

// Round 3
// 550.433 us; speedup vs baseline: 1.5357x; 1.0734x over previous
//
#include <hip/hip_runtime.h>

#define NSRC 20000
#define NTGT 20000
#define NN   20000
#define NEDGE 320000
#define COORD_MAX 10.0f

#define LDH 136    // ushort stride (272B, 16B-aligned)
#define TILE_N 64
#define LDN  264   // node kernel input stride (K=256)

typedef __attribute__((ext_vector_type(4))) float f32x4;
typedef __attribute__((ext_vector_type(8))) short short8;
typedef __attribute__((ext_vector_type(8))) __bf16 bf16x8;

static __device__ __forceinline__ f32x4 mfma16(short8 a, short8 b, f32x4 c) {
  return __builtin_amdgcn_mfma_f32_16x16x32_bf16(
      __builtin_bit_cast(bf16x8, a), __builtin_bit_cast(bf16x8, b), c, 0, 0, 0);
}
static __device__ __forceinline__ unsigned short f2bf(float f) {
  unsigned u = __builtin_bit_cast(unsigned, f);
  u += 0x7FFFu + ((u >> 16) & 1u);
  return (unsigned short)(u >> 16);
}
static __device__ __forceinline__ float bf2f(unsigned short u) {
  unsigned x = ((unsigned)u) << 16;
  return __builtin_bit_cast(float, x);
}
static __device__ __forceinline__ float sigm(float x) { return 1.f / (1.f + __expf(-x)); }
static __device__ __forceinline__ float silu_(float x) { return x * sigm(x); }

// ---------------------------------------------------------------------------
// Weight pack: fp32 [Kreal][128] row-major -> bf16 MFMA B-fragment order.
// ---------------------------------------------------------------------------
struct PackJobs {
  const float* w[11];
  unsigned short* o[11];
  int kreal[11];
  int nk[11];
};

__global__ void egnn_pack_all(PackJobs J) {
  const int job = blockIdx.y;
  const int nk = J.nk[job];
  const int idx = blockIdx.x * 256 + threadIdx.x;
  if (idx >= nk * 512) return;
  const float* w = J.w[job];
  const int kreal = J.kreal[job];
  const int lane = idx & 63;
  const int ct = (idx >> 6) & 7;
  const int kstep = idx >> 9;
  const int col = ct * 16 + (lane & 15);
  const int k0 = kstep * 32 + (lane >> 4) * 8;
  union { short8 s; unsigned short u[8]; } t;
#pragma unroll
  for (int j = 0; j < 8; ++j) {
    int k = k0 + j;
    t.u[j] = (k < kreal) ? f2bf(w[(size_t)k * 128 + col]) : (unsigned short)0;
  }
  reinterpret_cast<short8*>(J.o[job])[idx] = t.s;
}

// ---------------------------------------------------------------------------
// Precompute S1/T1 = X @ W (K=128), output bf16 [N][128]. 4 jobs via blockIdx.y.
// ---------------------------------------------------------------------------
struct PreJobs {
  const float* x[4];
  const unsigned short* w[4];
  unsigned short* o[4];
};

__global__ __launch_bounds__(256, 2) void egnn_pre(PreJobs J, int N) {
  __shared__ __align__(16) unsigned short sX[64 * LDH];
  const int job = blockIdx.y;
  const float* X = J.x[job];
  const unsigned short* W = J.w[job];
  unsigned short* O = J.o[job];
  const int n0 = blockIdx.x * 64;
  const int tid = threadIdx.x;

  for (int s = tid; s < 64 * 32; s += 256) {
    const int row = s >> 5;
    const int c4 = (s & 31) * 4;
    const int node = n0 + row;
    float4 v = {0.f, 0.f, 0.f, 0.f};
    if (node < N) v = reinterpret_cast<const float4*>(X + (size_t)node * 128)[s & 31];
    ushort4 b = {f2bf(v.x), f2bf(v.y), f2bf(v.z), f2bf(v.w)};
    *reinterpret_cast<ushort4*>(&sX[row * LDH + c4]) = b;
  }
  __syncthreads();

  const int lane = tid & 63, wid = tid >> 6;
  const int r16 = lane & 15, g4 = lane >> 4;
  const int rowBase = wid * 16;

  f32x4 acc[8];
#pragma unroll
  for (int ct = 0; ct < 8; ++ct) acc[ct] = f32x4{0.f, 0.f, 0.f, 0.f};
#pragma unroll
  for (int ks = 0; ks < 4; ++ks) {
    const short8 a = *reinterpret_cast<const short8*>(
        &sX[(rowBase + r16) * LDH + ks * 32 + g4 * 8]);
#pragma unroll
    for (int ct = 0; ct < 8; ++ct) {
      const short8 b = *reinterpret_cast<const short8*>(
          W + ((size_t)(ks * 8 + ct) * 64 + lane) * 8);
      acc[ct] = mfma16(a, b, acc[ct]);
    }
  }
#pragma unroll
  for (int ct = 0; ct < 8; ++ct) {
    const int col = ct * 16 + r16;
#pragma unroll
    for (int r = 0; r < 4; ++r) {
      const int node = n0 + rowBase + g4 * 4 + r;
      if (node < N) O[(size_t)node * 128 + col] = f2bf(acc[ct][r]);
    }
  }
}

// ---------------------------------------------------------------------------
// Sorting kernels (counting sort by tgt and by src).
// ---------------------------------------------------------------------------
__global__ void egnn_hist(const int* __restrict__ eTgt, const int* __restrict__ eSrc,
                          int* __restrict__ cntT, int* __restrict__ cntS) {
  const int e = blockIdx.x * 256 + threadIdx.x;
  if (e < NEDGE) {
    atomicAdd(&cntT[eTgt[e]], 1);
    atomicAdd(&cntS[eSrc[e]], 1);
  }
}

__global__ __launch_bounds__(1024) void egnn_scan(
    const int* __restrict__ c0, int* __restrict__ r0, int* __restrict__ o0,
    const int* __restrict__ c1, int* __restrict__ r1, int* __restrict__ o1, int n) {
  const int* cnt = blockIdx.x ? c1 : c0;
  int* rp = blockIdx.x ? r1 : r0;
  int* oc = blockIdx.x ? o1 : o0;
  __shared__ int sums[1024];
  const int tid = threadIdx.x;
  const int chunk = (n + 1023) / 1024;
  const int i0 = tid * chunk;
  int local = 0;
  for (int k = 0; k < chunk; ++k) {
    const int i = i0 + k;
    if (i < n) local += cnt[i];
  }
  sums[tid] = local;
  __syncthreads();
  for (int s = 1; s < 1024; s <<= 1) {
    int v = (tid >= s) ? sums[tid - s] : 0;
    __syncthreads();
    sums[tid] += v;
    __syncthreads();
  }
  int run = (tid == 0) ? 0 : sums[tid - 1];
  for (int k = 0; k < chunk; ++k) {
    const int i = i0 + k;
    if (i < n) { rp[i] = run; oc[i] = run; run += cnt[i]; }
  }
  if (tid == 1023) rp[n] = sums[1023];
}

__global__ void egnn_scatter(const int* __restrict__ eTgt, const int* __restrict__ eSrc,
                             int* __restrict__ offT, int* __restrict__ offS,
                             int* __restrict__ permT, int* __restrict__ permS) {
  const int e = blockIdx.x * 256 + threadIdx.x;
  if (e < NEDGE) {
    permT[atomicAdd(&offT[eTgt[e]], 1)] = e;
    permS[atomicAdd(&offS[eSrc[e]], 1)] = e;
  }
}

// ---------------------------------------------------------------------------
// Segmented reduction: agg[n] = sum over e rows of this node's edges (fp32).
// One wave per node, lane owns 2 columns.
// ---------------------------------------------------------------------------
__global__ __launch_bounds__(256) void egnn_agg(
    const unsigned short* __restrict__ ev, const int* __restrict__ perm,
    const int* __restrict__ rp, float* __restrict__ agg) {
  const int lane = threadIdx.x & 63;
  const int n = blockIdx.x * 4 + (threadIdx.x >> 6);
  const int j0 = rp[n], j1 = rp[n + 1];
  float a0 = 0.f, a1 = 0.f;
  int j = j0;
  for (; j + 4 <= j1; j += 4) {
    const int e0 = perm[j], e1 = perm[j + 1], e2 = perm[j + 2], e3 = perm[j + 3];
    const ushort2 v0 = *reinterpret_cast<const ushort2*>(ev + (size_t)e0 * 128 + lane * 2);
    const ushort2 v1 = *reinterpret_cast<const ushort2*>(ev + (size_t)e1 * 128 + lane * 2);
    const ushort2 v2 = *reinterpret_cast<const ushort2*>(ev + (size_t)e2 * 128 + lane * 2);
    const ushort2 v3 = *reinterpret_cast<const ushort2*>(ev + (size_t)e3 * 128 + lane * 2);
    a0 += bf2f(v0.x) + bf2f(v1.x) + bf2f(v2.x) + bf2f(v3.x);
    a1 += bf2f(v0.y) + bf2f(v1.y) + bf2f(v2.y) + bf2f(v3.y);
  }
  for (; j < j1; ++j) {
    const ushort2 v = *reinterpret_cast<const ushort2*>(ev + (size_t)perm[j] * 128 + lane * 2);
    a0 += bf2f(v.x); a1 += bf2f(v.y);
  }
  *reinterpret_cast<float2*>(agg + (size_t)n * 128 + lane * 2) = float2{a0, a1};
}

// ---------------------------------------------------------------------------
// Fused edge kernel. 256 edges/block, 4 waves x 64 edges.
// csr=1: write gated e rows (bf16) to eOut; csr=0: atomic scatter into agg.
// dirMask selects which direction(s) to process.
// ---------------------------------------------------------------------------
__global__ __launch_bounds__(256, 2) void egnn_edge(
    const unsigned short* __restrict__ S1A, const unsigned short* __restrict__ T1A,
    const unsigned short* __restrict__ S1B, const unsigned short* __restrict__ T1B,
    const float* __restrict__ srcC, const float* __restrict__ tgtC,
    const int* __restrict__ eSrc, const int* __restrict__ eTgt,
    const float* __restrict__ w1A, const float* __restrict__ b1A,
    const float* __restrict__ w1B, const float* __restrict__ b1B,
    const unsigned short* __restrict__ w2pA, const float* __restrict__ b2A,
    const float* __restrict__ wgA, const float* __restrict__ bgA,
    const unsigned short* __restrict__ w2pB, const float* __restrict__ b2B,
    const float* __restrict__ wgB, const float* __restrict__ bgB,
    const unsigned short* __restrict__ wc1p, const float* __restrict__ bc1,
    const float* __restrict__ wc2,
    float* __restrict__ aggA, float* __restrict__ aggB,
    float* __restrict__ trans, float* __restrict__ cntv,
    unsigned short* __restrict__ eOut, int dirMask, int csr)
{
  __shared__ __align__(16) unsigned short sH[4][64 * LDH];  // 69632 B
  __shared__ float sCD[256 * 3];
  __shared__ float sRad[256];
  __shared__ int sS[256];
  __shared__ int sT[256];

  const int tid = threadIdx.x;
  const int e0 = blockIdx.x * 256;

  {
    const int e = e0 + tid;
    const int s = eSrc[e], t = eTgt[e];
    sS[tid] = s; sT[tid] = t;
    const float dx = tgtC[t * 3 + 0] - srcC[s * 3 + 0];
    const float dy = tgtC[t * 3 + 1] - srcC[s * 3 + 1];
    const float dz = tgtC[t * 3 + 2] - srcC[s * 3 + 2];
    sCD[tid * 3 + 0] = dx; sCD[tid * 3 + 1] = dy; sCD[tid * 3 + 2] = dz;
    sRad[tid] = dx * dx + dy * dy + dz * dz;
  }
  __syncthreads();

  const int lane = tid & 63, wid = tid >> 6;
  const int r16 = lane & 15, g4 = lane >> 4;
  const int we = wid * 64;
  const int h32 = lane >> 5;
  const int c4 = (lane & 31) * 4;

  const float4 radA = *reinterpret_cast<const float4*>(w1A + 256 * 128 + c4);
  const float4 biaA = *reinterpret_cast<const float4*>(b1A + c4);
  const float4 radB = *reinterpret_cast<const float4*>(w1B + 256 * 128 + c4);
  const float4 biaB = *reinterpret_cast<const float4*>(b1B + c4);

  unsigned short* hT = sH[wid];

  for (int dir = 0; dir < 2; ++dir) {
    if (!(dirMask & (1 << dir))) continue;
    const unsigned short* S1 = dir ? S1B : S1A;
    const unsigned short* T1 = dir ? T1B : T1A;
    const float4 wr = dir ? radB : radA;
    const float4 bb = dir ? biaB : biaA;

    // ---- build h-tile: h = silu(S1[s] + T1[t] + rad*wr + bb), bf16 -> LDS
#pragma unroll 8
    for (int i = 0; i < 32; ++i) {
      const int row = 2 * i + h32;
      const int e = we + row;
      const int s = sS[e], t = sT[e];
      const float rad = sRad[e];
      const ushort4 a = *reinterpret_cast<const ushort4*>(S1 + (size_t)s * 128 + c4);
      const ushort4 b = *reinterpret_cast<const ushort4*>(T1 + (size_t)t * 128 + c4);
      ushort4 o;
      o.x = f2bf(silu_(bf2f(a.x) + bf2f(b.x) + rad * wr.x + bb.x));
      o.y = f2bf(silu_(bf2f(a.y) + bf2f(b.y) + rad * wr.y + bb.y));
      o.z = f2bf(silu_(bf2f(a.z) + bf2f(b.z) + rad * wr.z + bb.z));
      o.w = f2bf(silu_(bf2f(a.w) + bf2f(b.w) + rad * wr.w + bb.w));
      *reinterpret_cast<ushort4*>(&hT[row * LDH + c4]) = o;
    }

    // ---- GEMM2: 4 row-tiles x [16x128] @ [128x128]
    const unsigned short* w2p = dir ? w2pB : w2pA;
    f32x4 acc[4][8];
#pragma unroll
    for (int rt = 0; rt < 4; ++rt)
#pragma unroll
      for (int ct = 0; ct < 8; ++ct) acc[rt][ct] = f32x4{0.f, 0.f, 0.f, 0.f};
#pragma unroll
    for (int ks = 0; ks < 4; ++ks) {
      short8 a[4];
#pragma unroll
      for (int rt = 0; rt < 4; ++rt)
        a[rt] = *reinterpret_cast<const short8*>(
            &hT[(rt * 16 + r16) * LDH + ks * 32 + g4 * 8]);
#pragma unroll
      for (int ct = 0; ct < 8; ++ct) {
        const short8 b = *reinterpret_cast<const short8*>(
            w2p + ((size_t)(ks * 8 + ct) * 64 + lane) * 8);
#pragma unroll
        for (int rt = 0; rt < 4; ++rt) acc[rt][ct] = mfma16(a[rt], b, acc[rt][ct]);
      }
    }

    // ---- bias + SiLU + gate
    const float* b2 = dir ? b2B : b2A;
    const float* wg = dir ? wgB : wgA;
    const float bg = dir ? bgB[0] : bgA[0];
    float part[4][4];
#pragma unroll
    for (int rt = 0; rt < 4; ++rt)
#pragma unroll
      for (int r = 0; r < 4; ++r) part[rt][r] = 0.f;
#pragma unroll
    for (int ct = 0; ct < 8; ++ct) {
      const float b2v = b2[ct * 16 + r16];
      const float wgv = wg[ct * 16 + r16];
#pragma unroll
      for (int rt = 0; rt < 4; ++rt)
#pragma unroll
        for (int r = 0; r < 4; ++r) {
          const float e = silu_(acc[rt][ct][r] + b2v);
          acc[rt][ct][r] = e;
          part[rt][r] += e * wgv;
        }
    }
#pragma unroll
    for (int m = 1; m < 16; m <<= 1)
#pragma unroll
      for (int rt = 0; rt < 4; ++rt)
#pragma unroll
        for (int r = 0; r < 4; ++r) part[rt][r] += __shfl_xor(part[rt][r], m, 64);
#pragma unroll
    for (int rt = 0; rt < 4; ++rt)
#pragma unroll
      for (int r = 0; r < 4; ++r) {
        const float gate = sigm(part[rt][r] + bg);
#pragma unroll
        for (int ct = 0; ct < 8; ++ct) acc[rt][ct][r] *= gate;
      }

    // ---- stash gated e (bf16) into LDS (needed for coord GEMM and/or writeout)
    if (csr || dir == 0) {
#pragma unroll
      for (int rt = 0; rt < 4; ++rt)
#pragma unroll
        for (int ct = 0; ct < 8; ++ct)
#pragma unroll
          for (int r = 0; r < 4; ++r)
            hT[(rt * 16 + g4 * 4 + r) * LDH + ct * 16 + r16] = f2bf(acc[rt][ct][r]);
    }

    if (csr) {
      // coalesced write of the wave's 64 e-rows
#pragma unroll 4
      for (int it = 0; it < 32; ++it) {
        const int row = it * 2 + h32;
        *reinterpret_cast<ushort4*>(eOut + (size_t)(e0 + we + row) * 128 + c4) =
            *reinterpret_cast<const ushort4*>(&hT[row * LDH + c4]);
      }
    } else {
      const int* loc = dir ? sS : sT;
      float* agg = dir ? aggB : aggA;
#pragma unroll
      for (int rt = 0; rt < 4; ++rt) {
        int nidx[4];
#pragma unroll
        for (int r = 0; r < 4; ++r) nidx[r] = loc[we + rt * 16 + g4 * 4 + r];
#pragma unroll
        for (int ct = 0; ct < 8; ++ct)
#pragma unroll
          for (int r = 0; r < 4; ++r)
            atomicAdd(&agg[(size_t)nidx[r] * 128 + ct * 16 + r16], acc[rt][ct][r]);
      }
    }

    if (dir == 0) {
      // ---- coord GEMM on gated e_s2t
      f32x4 ac[4][8];
#pragma unroll
      for (int rt = 0; rt < 4; ++rt)
#pragma unroll
        for (int ct = 0; ct < 8; ++ct) ac[rt][ct] = f32x4{0.f, 0.f, 0.f, 0.f};
#pragma unroll
      for (int ks = 0; ks < 4; ++ks) {
        short8 a[4];
#pragma unroll
        for (int rt = 0; rt < 4; ++rt)
          a[rt] = *reinterpret_cast<const short8*>(
              &hT[(rt * 16 + r16) * LDH + ks * 32 + g4 * 8]);
#pragma unroll
        for (int ct = 0; ct < 8; ++ct) {
          const short8 b = *reinterpret_cast<const short8*>(
              wc1p + ((size_t)(ks * 8 + ct) * 64 + lane) * 8);
#pragma unroll
          for (int rt = 0; rt < 4; ++rt) ac[rt][ct] = mfma16(a[rt], b, ac[rt][ct]);
        }
      }
      float pc[4][4];
#pragma unroll
      for (int rt = 0; rt < 4; ++rt)
#pragma unroll
        for (int r = 0; r < 4; ++r) pc[rt][r] = 0.f;
#pragma unroll
      for (int ct = 0; ct < 8; ++ct) {
        const float bcv = bc1[ct * 16 + r16];
        const float w2v = wc2[ct * 16 + r16];
#pragma unroll
        for (int rt = 0; rt < 4; ++rt)
#pragma unroll
          for (int r = 0; r < 4; ++r)
            pc[rt][r] += silu_(ac[rt][ct][r] + bcv) * w2v;
      }
#pragma unroll
      for (int m = 1; m < 16; m <<= 1)
#pragma unroll
        for (int rt = 0; rt < 4; ++rt)
#pragma unroll
          for (int r = 0; r < 4; ++r) pc[rt][r] += __shfl_xor(pc[rt][r], m, 64);

#pragma unroll
      for (int rt = 0; rt < 4; ++rt)
#pragma unroll
        for (int r = 0; r < 4; ++r) {
          const int e = we + rt * 16 + g4 * 4 + r;
          const int n = sT[e];
          if (r16 < 3)
            atomicAdd(&trans[(size_t)n * 3 + r16], sCD[e * 3 + r16] * pc[rt][r]);
          else if (r16 == 3 && !csr)
            atomicAdd(&cntv[n], 1.0f);
        }
    }
  }
}

// ---------------------------------------------------------------------------
// Node kernel: out = feat + (silu([feat|agg] @ wn1 + bn1) @ wn2 + bn2)
// ---------------------------------------------------------------------------
__global__ __launch_bounds__(256, 2) void egnn_node(
    const float* __restrict__ feat, const float* __restrict__ agg,
    const unsigned short* __restrict__ w1p, const float* __restrict__ b1,
    const unsigned short* __restrict__ w2p, const float* __restrict__ b2,
    float* __restrict__ outp, int N)
{
  __shared__ __align__(16) unsigned short sIn[TILE_N * LDN];
  __shared__ __align__(16) unsigned short sH2[TILE_N * LDH];
  const int tid = threadIdx.x;
  const int n0 = blockIdx.x * TILE_N;

  {
    const int g = tid >> 5;
    const int l32 = tid & 31;
    for (int ri = g; ri < TILE_N * 2; ri += 8) {
      const int ln = ri >> 1;
      const int which = ri & 1;
      const int node = n0 + ln;
      float4 v = {0.f, 0.f, 0.f, 0.f};
      if (node < N)
        v = reinterpret_cast<const float4*>((which ? agg : feat) + (size_t)node * 128)[l32];
      ushort4 b;
      b.x = f2bf(v.x); b.y = f2bf(v.y); b.z = f2bf(v.z); b.w = f2bf(v.w);
      *reinterpret_cast<ushort4*>(&sIn[ln * LDN + which * 128 + l32 * 4]) = b;
    }
  }
  __syncthreads();

  const int lane = tid & 63;
  const int wid = tid >> 6;
  const int rowBase = wid * 16;
  const int r16 = lane & 15;
  const int g4 = lane >> 4;

  f32x4 acc[8];
#pragma unroll
  for (int ct = 0; ct < 8; ++ct) acc[ct] = f32x4{0.f, 0.f, 0.f, 0.f};
#pragma unroll
  for (int ks = 0; ks < 8; ++ks) {
    const short8 a = *reinterpret_cast<const short8*>(
        &sIn[(rowBase + r16) * LDN + ks * 32 + g4 * 8]);
#pragma unroll
    for (int ct = 0; ct < 8; ++ct) {
      const short8 b = *reinterpret_cast<const short8*>(
          w1p + ((size_t)(ks * 8 + ct) * 64 + lane) * 8);
      acc[ct] = mfma16(a, b, acc[ct]);
    }
  }
#pragma unroll
  for (int ct = 0; ct < 8; ++ct) {
    const int col = ct * 16 + r16;
    const float bias = b1[col];
#pragma unroll
    for (int r = 0; r < 4; ++r) {
      const float h = silu_(acc[ct][r] + bias);
      sH2[(rowBase + g4 * 4 + r) * LDH + col] = f2bf(h);
    }
  }

  f32x4 acc2[8];
#pragma unroll
  for (int ct = 0; ct < 8; ++ct) acc2[ct] = f32x4{0.f, 0.f, 0.f, 0.f};
#pragma unroll
  for (int ks = 0; ks < 4; ++ks) {
    const short8 a = *reinterpret_cast<const short8*>(
        &sH2[(rowBase + r16) * LDH + ks * 32 + g4 * 8]);
#pragma unroll
    for (int ct = 0; ct < 8; ++ct) {
      const short8 b = *reinterpret_cast<const short8*>(
          w2p + ((size_t)(ks * 8 + ct) * 64 + lane) * 8);
      acc2[ct] = mfma16(a, b, acc2[ct]);
    }
  }

#pragma unroll
  for (int ct = 0; ct < 8; ++ct) {
    const int col = ct * 16 + r16;
    const float bias = b2[col];
#pragma unroll
    for (int r = 0; r < 4; ++r) {
      const int node = n0 + rowBase + g4 * 4 + r;
      if (node < N)
        outp[(size_t)node * 128 + col] = feat[(size_t)node * 128 + col] + acc2[ct][r] + bias;
    }
  }
}

__global__ void egnn_coord(const float* __restrict__ srcC, const float* __restrict__ tgtC,
                           const float* __restrict__ trans, const float* __restrict__ cntv,
                           const int* __restrict__ rowptrT, int csr,
                           float* __restrict__ outSC, float* __restrict__ outTC) {
  const int i = blockIdx.x * 256 + threadIdx.x;
  if (i >= NTGT * 3) return;
  outSC[i] = srcC[i];
  const int n = i / 3;
  const float c = csr ? fmaxf((float)(rowptrT[n + 1] - rowptrT[n]), 1.f)
                      : fmaxf(cntv[n], 1.f);
  float a = trans[i] / c;
  a = fminf(fmaxf(a, -COORD_MAX), COORD_MAX);
  outTC[i] = tgtC[i] + a;
}

extern "C" void kernel_launch(void* const* d_in, const int* in_sizes, int n_in,
                              void* d_out, int out_size, void* d_ws, size_t ws_size,
                              hipStream_t stream) {
  const float* srcF = (const float*)d_in[0];
  const float* tgtF = (const float*)d_in[1];
  const float* srcC = (const float*)d_in[2];
  const float* tgtC = (const float*)d_in[3];
  const int* eSrc = (const int*)d_in[4];
  const int* eTgt = (const int*)d_in[5];
  const float* w1_s2t = (const float*)d_in[6];
  const float* b1_s2t = (const float*)d_in[7];
  const float* w2_s2t = (const float*)d_in[8];
  const float* b2_s2t = (const float*)d_in[9];
  const float* w1_t2s = (const float*)d_in[10];
  const float* b1_t2s = (const float*)d_in[11];
  const float* w2_t2s = (const float*)d_in[12];
  const float* b2_t2s = (const float*)d_in[13];
  const float* wg_s2t = (const float*)d_in[14];
  const float* bg_s2t = (const float*)d_in[15];
  const float* wg_t2s = (const float*)d_in[16];
  const float* bg_t2s = (const float*)d_in[17];
  const float* wc1 = (const float*)d_in[18];
  const float* bc1 = (const float*)d_in[19];
  const float* wc2 = (const float*)d_in[20];
  const float* wn1_t = (const float*)d_in[21];
  const float* bn1_t = (const float*)d_in[22];
  const float* wn2_t = (const float*)d_in[23];
  const float* bn2_t = (const float*)d_in[24];
  const float* wn1_s = (const float*)d_in[25];
  const float* bn1_s = (const float*)d_in[26];
  const float* wn2_s = (const float*)d_in[27];
  const float* bn2_s = (const float*)d_in[28];

  char* ws = (char*)d_ws;
  size_t off = 0;
  auto take = [&](size_t bytes) -> char* {
    char* p = ws + off;
    off = (off + bytes + 255) & ~(size_t)255;
    return p;
  };
  // fallback-shared region (kept compact at the front)
  float* aggA = (float*)take((size_t)NN * 128 * 4);
  float* aggB = (float*)take((size_t)NN * 128 * 4);
  float* trans = (float*)take((size_t)NN * 3 * 4);
  float* cntv = (float*)take((size_t)NN * 4);
  const size_t zeroFB = off;  // fallback zeroes [0, zeroFB)
  unsigned short* S1A = (unsigned short*)take((size_t)NN * 128 * 2);
  unsigned short* T1A = (unsigned short*)take((size_t)NN * 128 * 2);
  unsigned short* S1B = (unsigned short*)take((size_t)NN * 128 * 2);
  unsigned short* T1B = (unsigned short*)take((size_t)NN * 128 * 2);
  unsigned short* w1tA = (unsigned short*)take(4 * 4096 * 2);
  unsigned short* w1mA = (unsigned short*)take(4 * 4096 * 2);
  unsigned short* w1tB = (unsigned short*)take(4 * 4096 * 2);
  unsigned short* w1mB = (unsigned short*)take(4 * 4096 * 2);
  unsigned short* w2pA = (unsigned short*)take(4 * 4096 * 2);
  unsigned short* w2pB = (unsigned short*)take(4 * 4096 * 2);
  unsigned short* wc1p = (unsigned short*)take(4 * 4096 * 2);
  unsigned short* wn1pt = (unsigned short*)take(8 * 4096 * 2);
  unsigned short* wn2pt = (unsigned short*)take(4 * 4096 * 2);
  unsigned short* wn1ps = (unsigned short*)take(8 * 4096 * 2);
  unsigned short* wn2ps = (unsigned short*)take(4 * 4096 * 2);
  // CSR-only region
  int* cntT = (int*)take((size_t)NN * 4);
  int* cntS = (int*)take((size_t)NN * 4);
  const char* cntZeroStart = (const char*)cntT;
  const size_t cntZeroBytes = (size_t)((char*)cntS + NN * 4 - (char*)cntT);
  int* rowptrT = (int*)take((size_t)(NN + 1) * 4);
  int* rowptrS = (int*)take((size_t)(NN + 1) * 4);
  int* offT = (int*)take((size_t)NN * 4);
  int* offS = (int*)take((size_t)NN * 4);
  int* permT = (int*)take((size_t)NEDGE * 4);
  int* permS = (int*)take((size_t)NEDGE * 4);
  unsigned short* eBuf = (unsigned short*)take((size_t)NEDGE * 128 * 2);
  const bool csr = ws_size >= off;

  PackJobs PJ;
  PJ.w[0] = w1_s2t;             PJ.o[0] = w1tA;  PJ.kreal[0] = 128; PJ.nk[0] = 4;
  PJ.w[1] = w1_s2t + 128 * 128; PJ.o[1] = w1mA;  PJ.kreal[1] = 128; PJ.nk[1] = 4;
  PJ.w[2] = w1_t2s;             PJ.o[2] = w1tB;  PJ.kreal[2] = 128; PJ.nk[2] = 4;
  PJ.w[3] = w1_t2s + 128 * 128; PJ.o[3] = w1mB;  PJ.kreal[3] = 128; PJ.nk[3] = 4;
  PJ.w[4] = w2_s2t;             PJ.o[4] = w2pA;  PJ.kreal[4] = 128; PJ.nk[4] = 4;
  PJ.w[5] = w2_t2s;             PJ.o[5] = w2pB;  PJ.kreal[5] = 128; PJ.nk[5] = 4;
  PJ.w[6] = wc1;                PJ.o[6] = wc1p;  PJ.kreal[6] = 128; PJ.nk[6] = 4;
  PJ.w[7] = wn1_t;              PJ.o[7] = wn1pt; PJ.kreal[7] = 256; PJ.nk[7] = 8;
  PJ.w[8] = wn2_t;              PJ.o[8] = wn2pt; PJ.kreal[8] = 128; PJ.nk[8] = 4;
  PJ.w[9] = wn1_s;              PJ.o[9] = wn1ps; PJ.kreal[9] = 256; PJ.nk[9] = 8;
  PJ.w[10] = wn2_s;             PJ.o[10] = wn2ps; PJ.kreal[10] = 128; PJ.nk[10] = 4;

  PreJobs PR;
  PR.x[0] = srcF; PR.w[0] = w1tA; PR.o[0] = S1A;
  PR.x[1] = tgtF; PR.w[1] = w1mA; PR.o[1] = T1A;
  PR.x[2] = srcF; PR.w[2] = w1tB; PR.o[2] = S1B;
  PR.x[3] = tgtF; PR.w[3] = w1mB; PR.o[3] = T1B;

  float* outSrc = (float*)d_out;
  float* outTgt = outSrc + (size_t)NSRC * 128;
  float* outSC  = outTgt + (size_t)NTGT * 128;
  float* outTC  = outSC + (size_t)NSRC * 3;

  if (csr) {
    // zero: trans (+cntv pad) and hist counters
    hipMemsetAsync(trans, 0, (size_t)((char*)cntv + NN * 4 - (char*)trans), stream);
    hipMemsetAsync((void*)cntZeroStart, 0, cntZeroBytes, stream);

    egnn_pack_all<<<dim3(16, 11), 256, 0, stream>>>(PJ);
    egnn_pre<<<dim3(313, 4), 256, 0, stream>>>(PR, NSRC);

    egnn_hist<<<NEDGE / 256, 256, 0, stream>>>(eTgt, eSrc, cntT, cntS);
    egnn_scan<<<2, 1024, 0, stream>>>(cntT, rowptrT, offT, cntS, rowptrS, offS, NN);
    egnn_scatter<<<NEDGE / 256, 256, 0, stream>>>(eTgt, eSrc, offT, offS, permT, permS);

    // dir 0 (s2t): e rows -> eBuf, then reduce by tgt
    egnn_edge<<<NEDGE / 256, 256, 0, stream>>>(
        S1A, T1A, S1B, T1B, srcC, tgtC, eSrc, eTgt,
        w1_s2t, b1_s2t, w1_t2s, b1_t2s,
        w2pA, b2_s2t, wg_s2t, bg_s2t,
        w2pB, b2_t2s, wg_t2s, bg_t2s,
        wc1p, bc1, wc2,
        aggA, aggB, trans, cntv, eBuf, /*dirMask=*/1, /*csr=*/1);
    egnn_agg<<<NN / 4, 256, 0, stream>>>(eBuf, permT, rowptrT, aggA);

    // dir 1 (t2s): reuse eBuf, reduce by src
    egnn_edge<<<NEDGE / 256, 256, 0, stream>>>(
        S1A, T1A, S1B, T1B, srcC, tgtC, eSrc, eTgt,
        w1_s2t, b1_s2t, w1_t2s, b1_t2s,
        w2pA, b2_s2t, wg_s2t, bg_s2t,
        w2pB, b2_t2s, wg_t2s, bg_t2s,
        wc1p, bc1, wc2,
        aggA, aggB, trans, cntv, eBuf, /*dirMask=*/2, /*csr=*/1);
    egnn_agg<<<NN / 4, 256, 0, stream>>>(eBuf, permS, rowptrS, aggB);

    egnn_node<<<(NTGT + TILE_N - 1) / TILE_N, 256, 0, stream>>>(
        tgtF, aggA, wn1pt, bn1_t, wn2pt, bn2_t, outTgt, NTGT);
    egnn_node<<<(NSRC + TILE_N - 1) / TILE_N, 256, 0, stream>>>(
        srcF, aggB, wn1ps, bn1_s, wn2ps, bn2_s, outSrc, NSRC);

    egnn_coord<<<(NTGT * 3 + 255) / 256, 256, 0, stream>>>(
        srcC, tgtC, trans, cntv, rowptrT, 1, outSC, outTC);
  } else {
    // fallback: round-2 atomic-scatter path
    hipMemsetAsync(ws, 0, zeroFB, stream);
    egnn_pack_all<<<dim3(16, 11), 256, 0, stream>>>(PJ);
    egnn_pre<<<dim3(313, 4), 256, 0, stream>>>(PR, NSRC);

    egnn_edge<<<NEDGE / 256, 256, 0, stream>>>(
        S1A, T1A, S1B, T1B, srcC, tgtC, eSrc, eTgt,
        w1_s2t, b1_s2t, w1_t2s, b1_t2s,
        w2pA, b2_s2t, wg_s2t, bg_s2t,
        w2pB, b2_t2s, wg_t2s, bg_t2s,
        wc1p, bc1, wc2,
        aggA, aggB, trans, cntv, nullptr, /*dirMask=*/3, /*csr=*/0);

    egnn_node<<<(NTGT + TILE_N - 1) / TILE_N, 256, 0, stream>>>(
        tgtF, aggA, wn1pt, bn1_t, wn2pt, bn2_t, outTgt, NTGT);
    egnn_node<<<(NSRC + TILE_N - 1) / TILE_N, 256, 0, stream>>>(
        srcF, aggB, wn1ps, bn1_s, wn2ps, bn2_s, outSrc, NSRC);

    egnn_coord<<<(NTGT * 3 + 255) / 256, 256, 0, stream>>>(
        srcC, tgtC, trans, cntv, nullptr, 0, outSC, outTC);
  }
}

// Round 4
// 437.627 us; speedup vs baseline: 1.9316x; 1.2578x over previous
//
#include <hip/hip_runtime.h>

#define NN 20000
#define NEDGE 320000
#define COORD_MAX 10.0f

#define LDH 136    // ushort stride (272B, 16B-aligned)
#define TILE_N 64
#define LDN  264   // node kernel input stride (K=256)

typedef __attribute__((ext_vector_type(4))) float f32x4;
typedef __attribute__((ext_vector_type(8))) short short8;
typedef __attribute__((ext_vector_type(8))) __bf16 bf16x8;

static __device__ __forceinline__ f32x4 mfma16(short8 a, short8 b, f32x4 c) {
  return __builtin_amdgcn_mfma_f32_16x16x32_bf16(
      __builtin_bit_cast(bf16x8, a), __builtin_bit_cast(bf16x8, b), c, 0, 0, 0);
}
static __device__ __forceinline__ unsigned short f2bf(float f) {
  unsigned u = __builtin_bit_cast(unsigned, f);
  u += 0x7FFFu + ((u >> 16) & 1u);
  return (unsigned short)(u >> 16);
}
static __device__ __forceinline__ float bf2f(unsigned short u) {
  unsigned x = ((unsigned)u) << 16;
  return __builtin_bit_cast(float, x);
}
static __device__ __forceinline__ float sigm(float x) { return 1.f / (1.f + __expf(-x)); }
static __device__ __forceinline__ float silu_(float x) { return x * sigm(x); }

// ---------------------------------------------------------------------------
// Weight pack: fp32 [Kreal][128] row-major -> bf16 MFMA B-fragment order.
// ---------------------------------------------------------------------------
struct PackJobs {
  const float* w[11];
  unsigned short* o[11];
  int kreal[11];
  int nk[11];
};

__global__ void egnn_pack_all(PackJobs J) {
  const int job = blockIdx.y;
  const int nk = J.nk[job];
  const int idx = blockIdx.x * 256 + threadIdx.x;
  if (idx >= nk * 512) return;
  const float* w = J.w[job];
  const int kreal = J.kreal[job];
  const int lane = idx & 63;
  const int ct = (idx >> 6) & 7;
  const int kstep = idx >> 9;
  const int col = ct * 16 + (lane & 15);
  const int k0 = kstep * 32 + (lane >> 4) * 8;
  union { short8 s; unsigned short u[8]; } t;
#pragma unroll
  for (int j = 0; j < 8; ++j) {
    int k = k0 + j;
    t.u[j] = (k < kreal) ? f2bf(w[(size_t)k * 128 + col]) : (unsigned short)0;
  }
  reinterpret_cast<short8*>(J.o[job])[idx] = t.s;
}

// ---------------------------------------------------------------------------
// Precompute S1/T1 = X @ W (K=128), output bf16 [N][128]. 4 jobs via blockIdx.y.
// ---------------------------------------------------------------------------
struct PreJobs {
  const float* x[4];
  const unsigned short* w[4];
  unsigned short* o[4];
};

__global__ __launch_bounds__(256, 2) void egnn_pre(PreJobs J, int N) {
  __shared__ __align__(16) unsigned short sX[64 * LDH];
  const int job = blockIdx.y;
  const float* X = J.x[job];
  const unsigned short* W = J.w[job];
  unsigned short* O = J.o[job];
  const int n0 = blockIdx.x * 64;
  const int tid = threadIdx.x;

  for (int s = tid; s < 64 * 32; s += 256) {
    const int row = s >> 5;
    const int c4 = (s & 31) * 4;
    const int node = n0 + row;
    float4 v = {0.f, 0.f, 0.f, 0.f};
    if (node < N) v = reinterpret_cast<const float4*>(X + (size_t)node * 128)[s & 31];
    ushort4 b = {f2bf(v.x), f2bf(v.y), f2bf(v.z), f2bf(v.w)};
    *reinterpret_cast<ushort4*>(&sX[row * LDH + c4]) = b;
  }
  __syncthreads();

  const int lane = tid & 63, wid = tid >> 6;
  const int r16 = lane & 15, g4 = lane >> 4;
  const int rowBase = wid * 16;

  f32x4 acc[8];
#pragma unroll
  for (int ct = 0; ct < 8; ++ct) acc[ct] = f32x4{0.f, 0.f, 0.f, 0.f};
#pragma unroll
  for (int ks = 0; ks < 4; ++ks) {
    const short8 a = *reinterpret_cast<const short8*>(
        &sX[(rowBase + r16) * LDH + ks * 32 + g4 * 8]);
#pragma unroll
    for (int ct = 0; ct < 8; ++ct) {
      const short8 b = *reinterpret_cast<const short8*>(
          W + ((size_t)(ks * 8 + ct) * 64 + lane) * 8);
      acc[ct] = mfma16(a, b, acc[ct]);
    }
  }
#pragma unroll
  for (int ct = 0; ct < 8; ++ct) {
    const int col = ct * 16 + r16;
#pragma unroll
    for (int r = 0; r < 4; ++r) {
      const int node = n0 + rowBase + g4 * 4 + r;
      if (node < N) O[(size_t)node * 128 + col] = f2bf(acc[ct][r]);
    }
  }
}

// ---------------------------------------------------------------------------
// Counting sort by tgt and by src.
// ---------------------------------------------------------------------------
__global__ void egnn_hist(const int* __restrict__ eTgt, const int* __restrict__ eSrc,
                          int* __restrict__ cntT, int* __restrict__ cntS) {
  const int e = blockIdx.x * 256 + threadIdx.x;
  if (e < NEDGE) {
    atomicAdd(&cntT[eTgt[e]], 1);
    atomicAdd(&cntS[eSrc[e]], 1);
  }
}

__global__ __launch_bounds__(1024) void egnn_scan(
    const int* __restrict__ c0, int* __restrict__ r0, int* __restrict__ o0,
    const int* __restrict__ c1, int* __restrict__ r1, int* __restrict__ o1, int n) {
  const int* cnt = blockIdx.x ? c1 : c0;
  int* rp = blockIdx.x ? r1 : r0;
  int* oc = blockIdx.x ? o1 : o0;
  __shared__ int sums[1024];
  const int tid = threadIdx.x;
  const int chunk = (n + 1023) / 1024;
  const int i0 = tid * chunk;
  int local = 0;
  for (int k = 0; k < chunk; ++k) {
    const int i = i0 + k;
    if (i < n) local += cnt[i];
  }
  sums[tid] = local;
  __syncthreads();
  for (int s = 1; s < 1024; s <<= 1) {
    int v = (tid >= s) ? sums[tid - s] : 0;
    __syncthreads();
    sums[tid] += v;
    __syncthreads();
  }
  int run = (tid == 0) ? 0 : sums[tid - 1];
  for (int k = 0; k < chunk; ++k) {
    const int i = i0 + k;
    if (i < n) { rp[i] = run; oc[i] = run; run += cnt[i]; }
  }
  if (tid == 1023) rp[n] = sums[1023];
}

__global__ void egnn_scatter(const int* __restrict__ eTgt, const int* __restrict__ eSrc,
                             int* __restrict__ offT, int* __restrict__ offS,
                             int* __restrict__ permT, int* __restrict__ permS) {
  const int e = blockIdx.x * 256 + threadIdx.x;
  if (e < NEDGE) {
    permT[atomicAdd(&offT[eTgt[e]], 1)] = e;
    permS[atomicAdd(&offS[eSrc[e]], 1)] = e;
  }
}

// ---------------------------------------------------------------------------
// Fused edge kernel, sorted order. 128 edges/block, 4 waves x 32 edges.
// dir = dirBase (>=0) or blockIdx.y. Writes gated e rows (bf16) to eOut at
// SORTED position; dir0 additionally coord-MLP -> wtBuf (sorted position).
// ---------------------------------------------------------------------------
struct EdgePtrs {
  const int* perm[2];
  unsigned short* eOut[2];
};

__global__ __launch_bounds__(256, 4) void egnn_edge(
    const unsigned short* __restrict__ S1A, const unsigned short* __restrict__ T1A,
    const unsigned short* __restrict__ S1B, const unsigned short* __restrict__ T1B,
    const float* __restrict__ srcC, const float* __restrict__ tgtC,
    const int* __restrict__ eSrc, const int* __restrict__ eTgt,
    const float* __restrict__ w1A, const float* __restrict__ b1A,
    const float* __restrict__ w1B, const float* __restrict__ b1B,
    const unsigned short* __restrict__ w2pA, const float* __restrict__ b2A,
    const float* __restrict__ wgA, const float* __restrict__ bgA,
    const unsigned short* __restrict__ w2pB, const float* __restrict__ b2B,
    const float* __restrict__ wgB, const float* __restrict__ bgB,
    const unsigned short* __restrict__ wc1p, const float* __restrict__ bc1,
    const float* __restrict__ wc2,
    EdgePtrs EP, float* __restrict__ wtBuf, int dirBase)
{
  __shared__ __align__(16) unsigned short sH[4][32 * LDH];  // 34816 B
  __shared__ float sCD[128 * 3];
  __shared__ float sRad[128];
  __shared__ int sS[128];
  __shared__ int sT[128];

  const int dir = (dirBase >= 0) ? dirBase : (int)blockIdx.y;
  const int tid = threadIdx.x;
  const int j0 = blockIdx.x * 128;
  const int* __restrict__ perm = EP.perm[dir];
  unsigned short* __restrict__ eOut = EP.eOut[dir];

  if (tid < 128) {
    const int e = perm[j0 + tid];
    const int s = eSrc[e], t = eTgt[e];
    sS[tid] = s; sT[tid] = t;
    const float dx = tgtC[t * 3 + 0] - srcC[s * 3 + 0];
    const float dy = tgtC[t * 3 + 1] - srcC[s * 3 + 1];
    const float dz = tgtC[t * 3 + 2] - srcC[s * 3 + 2];
    sCD[tid * 3 + 0] = dx; sCD[tid * 3 + 1] = dy; sCD[tid * 3 + 2] = dz;
    sRad[tid] = dx * dx + dy * dy + dz * dz;
  }
  __syncthreads();

  const int lane = tid & 63, wid = tid >> 6;
  const int r16 = lane & 15, g4 = lane >> 4;
  const int we = wid * 32;
  const int h32 = lane >> 5;
  const int c4 = (lane & 31) * 4;

  const unsigned short* S1 = dir ? S1B : S1A;
  const unsigned short* T1 = dir ? T1B : T1A;
  const float* w1 = dir ? w1B : w1A;
  const float* b1 = dir ? b1B : b1A;
  const float4 wr = *reinterpret_cast<const float4*>(w1 + 256 * 128 + c4);
  const float4 bb = *reinterpret_cast<const float4*>(b1 + c4);

  unsigned short* hT = sH[wid];

  // ---- build h-tile: h = silu(S1[s] + T1[t] + rad*wr + bb), bf16 -> LDS
#pragma unroll 8
  for (int i = 0; i < 16; ++i) {
    const int row = 2 * i + h32;
    const int e = we + row;
    const int s = sS[e], t = sT[e];
    const float rad = sRad[e];
    const ushort4 a = *reinterpret_cast<const ushort4*>(S1 + (size_t)s * 128 + c4);
    const ushort4 b = *reinterpret_cast<const ushort4*>(T1 + (size_t)t * 128 + c4);
    ushort4 o;
    o.x = f2bf(silu_(bf2f(a.x) + bf2f(b.x) + rad * wr.x + bb.x));
    o.y = f2bf(silu_(bf2f(a.y) + bf2f(b.y) + rad * wr.y + bb.y));
    o.z = f2bf(silu_(bf2f(a.z) + bf2f(b.z) + rad * wr.z + bb.z));
    o.w = f2bf(silu_(bf2f(a.w) + bf2f(b.w) + rad * wr.w + bb.w));
    *reinterpret_cast<ushort4*>(&hT[row * LDH + c4]) = o;
  }

  // ---- GEMM2: 2 row-tiles x [16x128] @ [128x128]
  const unsigned short* w2p = dir ? w2pB : w2pA;
  f32x4 acc[2][8];
#pragma unroll
  for (int rt = 0; rt < 2; ++rt)
#pragma unroll
    for (int ct = 0; ct < 8; ++ct) acc[rt][ct] = f32x4{0.f, 0.f, 0.f, 0.f};
#pragma unroll
  for (int ks = 0; ks < 4; ++ks) {
    short8 a[2];
#pragma unroll
    for (int rt = 0; rt < 2; ++rt)
      a[rt] = *reinterpret_cast<const short8*>(
          &hT[(rt * 16 + r16) * LDH + ks * 32 + g4 * 8]);
#pragma unroll
    for (int ct = 0; ct < 8; ++ct) {
      const short8 b = *reinterpret_cast<const short8*>(
          w2p + ((size_t)(ks * 8 + ct) * 64 + lane) * 8);
#pragma unroll
      for (int rt = 0; rt < 2; ++rt) acc[rt][ct] = mfma16(a[rt], b, acc[rt][ct]);
    }
  }

  // ---- bias + SiLU + gate
  const float* b2 = dir ? b2B : b2A;
  const float* wg = dir ? wgB : wgA;
  const float bg = dir ? bgB[0] : bgA[0];
  float part[2][4];
#pragma unroll
  for (int rt = 0; rt < 2; ++rt)
#pragma unroll
    for (int r = 0; r < 4; ++r) part[rt][r] = 0.f;
#pragma unroll
  for (int ct = 0; ct < 8; ++ct) {
    const float b2v = b2[ct * 16 + r16];
    const float wgv = wg[ct * 16 + r16];
#pragma unroll
    for (int rt = 0; rt < 2; ++rt)
#pragma unroll
      for (int r = 0; r < 4; ++r) {
        const float e = silu_(acc[rt][ct][r] + b2v);
        acc[rt][ct][r] = e;
        part[rt][r] += e * wgv;
      }
  }
#pragma unroll
  for (int m = 1; m < 16; m <<= 1)
#pragma unroll
    for (int rt = 0; rt < 2; ++rt)
#pragma unroll
      for (int r = 0; r < 4; ++r) part[rt][r] += __shfl_xor(part[rt][r], m, 64);
#pragma unroll
  for (int rt = 0; rt < 2; ++rt)
#pragma unroll
    for (int r = 0; r < 4; ++r) {
      const float gate = sigm(part[rt][r] + bg);
#pragma unroll
      for (int ct = 0; ct < 8; ++ct) acc[rt][ct][r] *= gate;
    }

  // ---- stash gated e (bf16) into LDS (transpose for writeout + coord A-frag)
#pragma unroll
  for (int rt = 0; rt < 2; ++rt)
#pragma unroll
    for (int ct = 0; ct < 8; ++ct)
#pragma unroll
      for (int r = 0; r < 4; ++r)
        hT[(rt * 16 + g4 * 4 + r) * LDH + ct * 16 + r16] = f2bf(acc[rt][ct][r]);

  // ---- coalesced write of the wave's 32 e-rows at SORTED positions
#pragma unroll 4
  for (int it = 0; it < 16; ++it) {
    const int row = it * 2 + h32;
    *reinterpret_cast<ushort4*>(eOut + (size_t)(j0 + we + row) * 128 + c4) =
        *reinterpret_cast<const ushort4*>(&hT[row * LDH + c4]);
  }

  if (dir == 0) {
    // ---- coord GEMM on gated e_s2t
    f32x4 ac[2][8];
#pragma unroll
    for (int rt = 0; rt < 2; ++rt)
#pragma unroll
      for (int ct = 0; ct < 8; ++ct) ac[rt][ct] = f32x4{0.f, 0.f, 0.f, 0.f};
#pragma unroll
    for (int ks = 0; ks < 4; ++ks) {
      short8 a[2];
#pragma unroll
      for (int rt = 0; rt < 2; ++rt)
        a[rt] = *reinterpret_cast<const short8*>(
            &hT[(rt * 16 + r16) * LDH + ks * 32 + g4 * 8]);
#pragma unroll
      for (int ct = 0; ct < 8; ++ct) {
        const short8 b = *reinterpret_cast<const short8*>(
            wc1p + ((size_t)(ks * 8 + ct) * 64 + lane) * 8);
#pragma unroll
        for (int rt = 0; rt < 2; ++rt) ac[rt][ct] = mfma16(a[rt], b, ac[rt][ct]);
      }
    }
    float pc[2][4];
#pragma unroll
    for (int rt = 0; rt < 2; ++rt)
#pragma unroll
      for (int r = 0; r < 4; ++r) pc[rt][r] = 0.f;
#pragma unroll
    for (int ct = 0; ct < 8; ++ct) {
      const float bcv = bc1[ct * 16 + r16];
      const float w2v = wc2[ct * 16 + r16];
#pragma unroll
      for (int rt = 0; rt < 2; ++rt)
#pragma unroll
        for (int r = 0; r < 4; ++r)
          pc[rt][r] += silu_(ac[rt][ct][r] + bcv) * w2v;
    }
#pragma unroll
    for (int m = 1; m < 16; m <<= 1)
#pragma unroll
      for (int rt = 0; rt < 2; ++rt)
#pragma unroll
        for (int r = 0; r < 4; ++r) pc[rt][r] += __shfl_xor(pc[rt][r], m, 64);

    // per-edge weighted coord diff -> wtBuf (sorted position), no atomics
#pragma unroll
    for (int rt = 0; rt < 2; ++rt)
#pragma unroll
      for (int r = 0; r < 4; ++r) {
        if (r16 == 0) {
          const int el = we + rt * 16 + g4 * 4 + r;
          const float p = pc[rt][r];
          const float4 w = {sCD[el * 3 + 0] * p, sCD[el * 3 + 1] * p,
                            sCD[el * 3 + 2] * p, 0.f};
          *reinterpret_cast<float4*>(wtBuf + (size_t)(j0 + el) * 4) = w;
        }
      }
  }
}

// ---------------------------------------------------------------------------
// Segmented reduction over CONTIGUOUS sorted rows: agg[n] = sum rows rp[n]..rp[n+1).
// One wave per node, lane owns 2 columns.
// ---------------------------------------------------------------------------
__global__ __launch_bounds__(256) void egnn_agg(
    const unsigned short* __restrict__ ev, const int* __restrict__ rp,
    float* __restrict__ agg) {
  const int lane = threadIdx.x & 63;
  const int n = blockIdx.x * 4 + (threadIdx.x >> 6);
  const int j0 = rp[n], j1 = rp[n + 1];
  float a0 = 0.f, a1 = 0.f;
  const unsigned short* p = ev + (size_t)j0 * 128 + lane * 2;
  int m = j1 - j0;
  for (; m >= 4; m -= 4) {
    const ushort2 v0 = *reinterpret_cast<const ushort2*>(p);
    const ushort2 v1 = *reinterpret_cast<const ushort2*>(p + 128);
    const ushort2 v2 = *reinterpret_cast<const ushort2*>(p + 256);
    const ushort2 v3 = *reinterpret_cast<const ushort2*>(p + 384);
    p += 512;
    a0 += bf2f(v0.x) + bf2f(v1.x) + bf2f(v2.x) + bf2f(v3.x);
    a1 += bf2f(v0.y) + bf2f(v1.y) + bf2f(v2.y) + bf2f(v3.y);
  }
  for (; m > 0; --m) {
    const ushort2 v = *reinterpret_cast<const ushort2*>(p);
    p += 128;
    a0 += bf2f(v.x); a1 += bf2f(v.y);
  }
  *reinterpret_cast<float2*>(agg + (size_t)n * 128 + lane * 2) = float2{a0, a1};
}

// ---------------------------------------------------------------------------
// Coord finalize: segmented sum of wtBuf by tgt (contiguous), /max(deg,1),
// clip, add; also copy src coords.
// ---------------------------------------------------------------------------
__global__ void egnn_coord(const float* __restrict__ srcC, const float* __restrict__ tgtC,
                           const float* __restrict__ wt, const int* __restrict__ rp,
                           float* __restrict__ outSC, float* __restrict__ outTC) {
  const int n = blockIdx.x * 256 + threadIdx.x;
  if (n >= NN) return;
  outSC[n * 3 + 0] = srcC[n * 3 + 0];
  outSC[n * 3 + 1] = srcC[n * 3 + 1];
  outSC[n * 3 + 2] = srcC[n * 3 + 2];
  const int j0 = rp[n], j1 = rp[n + 1];
  float ax = 0.f, ay = 0.f, az = 0.f;
  for (int j = j0; j < j1; ++j) {
    const float4 v = *reinterpret_cast<const float4*>(wt + (size_t)j * 4);
    ax += v.x; ay += v.y; az += v.z;
  }
  const float c = fmaxf((float)(j1 - j0), 1.f);
  ax = fminf(fmaxf(ax / c, -COORD_MAX), COORD_MAX);
  ay = fminf(fmaxf(ay / c, -COORD_MAX), COORD_MAX);
  az = fminf(fmaxf(az / c, -COORD_MAX), COORD_MAX);
  outTC[n * 3 + 0] = tgtC[n * 3 + 0] + ax;
  outTC[n * 3 + 1] = tgtC[n * 3 + 1] + ay;
  outTC[n * 3 + 2] = tgtC[n * 3 + 2] + az;
}

// ---------------------------------------------------------------------------
// Node kernel: out = feat + (silu([feat|agg] @ wn1 + bn1) @ wn2 + bn2)
// ---------------------------------------------------------------------------
__global__ __launch_bounds__(256, 2) void egnn_node(
    const float* __restrict__ feat, const float* __restrict__ agg,
    const unsigned short* __restrict__ w1p, const float* __restrict__ b1,
    const unsigned short* __restrict__ w2p, const float* __restrict__ b2,
    float* __restrict__ outp, int N)
{
  __shared__ __align__(16) unsigned short sIn[TILE_N * LDN];
  __shared__ __align__(16) unsigned short sH2[TILE_N * LDH];
  const int tid = threadIdx.x;
  const int n0 = blockIdx.x * TILE_N;

  {
    const int g = tid >> 5;
    const int l32 = tid & 31;
    for (int ri = g; ri < TILE_N * 2; ri += 8) {
      const int ln = ri >> 1;
      const int which = ri & 1;
      const int node = n0 + ln;
      float4 v = {0.f, 0.f, 0.f, 0.f};
      if (node < N)
        v = reinterpret_cast<const float4*>((which ? agg : feat) + (size_t)node * 128)[l32];
      ushort4 b;
      b.x = f2bf(v.x); b.y = f2bf(v.y); b.z = f2bf(v.z); b.w = f2bf(v.w);
      *reinterpret_cast<ushort4*>(&sIn[ln * LDN + which * 128 + l32 * 4]) = b;
    }
  }
  __syncthreads();

  const int lane = tid & 63;
  const int wid = tid >> 6;
  const int rowBase = wid * 16;
  const int r16 = lane & 15;
  const int g4 = lane >> 4;

  f32x4 acc[8];
#pragma unroll
  for (int ct = 0; ct < 8; ++ct) acc[ct] = f32x4{0.f, 0.f, 0.f, 0.f};
#pragma unroll
  for (int ks = 0; ks < 8; ++ks) {
    const short8 a = *reinterpret_cast<const short8*>(
        &sIn[(rowBase + r16) * LDN + ks * 32 + g4 * 8]);
#pragma unroll
    for (int ct = 0; ct < 8; ++ct) {
      const short8 b = *reinterpret_cast<const short8*>(
          w1p + ((size_t)(ks * 8 + ct) * 64 + lane) * 8);
      acc[ct] = mfma16(a, b, acc[ct]);
    }
  }
#pragma unroll
  for (int ct = 0; ct < 8; ++ct) {
    const int col = ct * 16 + r16;
    const float bias = b1[col];
#pragma unroll
    for (int r = 0; r < 4; ++r) {
      const float h = silu_(acc[ct][r] + bias);
      sH2[(rowBase + g4 * 4 + r) * LDH + col] = f2bf(h);
    }
  }

  f32x4 acc2[8];
#pragma unroll
  for (int ct = 0; ct < 8; ++ct) acc2[ct] = f32x4{0.f, 0.f, 0.f, 0.f};
#pragma unroll
  for (int ks = 0; ks < 4; ++ks) {
    const short8 a = *reinterpret_cast<const short8*>(
        &sH2[(rowBase + r16) * LDH + ks * 32 + g4 * 8]);
#pragma unroll
    for (int ct = 0; ct < 8; ++ct) {
      const short8 b = *reinterpret_cast<const short8*>(
          w2p + ((size_t)(ks * 8 + ct) * 64 + lane) * 8);
      acc2[ct] = mfma16(a, b, acc2[ct]);
    }
  }

#pragma unroll
  for (int ct = 0; ct < 8; ++ct) {
    const int col = ct * 16 + r16;
    const float bias = b2[col];
#pragma unroll
    for (int r = 0; r < 4; ++r) {
      const int node = n0 + rowBase + g4 * 4 + r;
      if (node < N)
        outp[(size_t)node * 128 + col] = feat[(size_t)node * 128 + col] + acc2[ct][r] + bias;
    }
  }
}

extern "C" void kernel_launch(void* const* d_in, const int* in_sizes, int n_in,
                              void* d_out, int out_size, void* d_ws, size_t ws_size,
                              hipStream_t stream) {
  const float* srcF = (const float*)d_in[0];
  const float* tgtF = (const float*)d_in[1];
  const float* srcC = (const float*)d_in[2];
  const float* tgtC = (const float*)d_in[3];
  const int* eSrc = (const int*)d_in[4];
  const int* eTgt = (const int*)d_in[5];
  const float* w1_s2t = (const float*)d_in[6];
  const float* b1_s2t = (const float*)d_in[7];
  const float* w2_s2t = (const float*)d_in[8];
  const float* b2_s2t = (const float*)d_in[9];
  const float* w1_t2s = (const float*)d_in[10];
  const float* b1_t2s = (const float*)d_in[11];
  const float* w2_t2s = (const float*)d_in[12];
  const float* b2_t2s = (const float*)d_in[13];
  const float* wg_s2t = (const float*)d_in[14];
  const float* bg_s2t = (const float*)d_in[15];
  const float* wg_t2s = (const float*)d_in[16];
  const float* bg_t2s = (const float*)d_in[17];
  const float* wc1 = (const float*)d_in[18];
  const float* bc1 = (const float*)d_in[19];
  const float* wc2 = (const float*)d_in[20];
  const float* wn1_t = (const float*)d_in[21];
  const float* bn1_t = (const float*)d_in[22];
  const float* wn2_t = (const float*)d_in[23];
  const float* bn2_t = (const float*)d_in[24];
  const float* wn1_s = (const float*)d_in[25];
  const float* bn1_s = (const float*)d_in[26];
  const float* wn2_s = (const float*)d_in[27];
  const float* bn2_s = (const float*)d_in[28];

  char* ws = (char*)d_ws;
  size_t off = 0;
  auto take = [&](size_t bytes) -> char* {
    char* p = ws + off;
    off = (off + bytes + 255) & ~(size_t)255;
    return p;
  };
  float* aggA = (float*)take((size_t)NN * 128 * 4);           // 10.24 MB
  float* aggB = (float*)take((size_t)NN * 128 * 4);           // 10.24 MB (aliased wtBuf)
  float* wtBuf = aggB;                                        // NEDGE*4*4 = 5.12 MB <= aggB
  unsigned short* S1A = (unsigned short*)take((size_t)NN * 128 * 2);
  unsigned short* T1A = (unsigned short*)take((size_t)NN * 128 * 2);
  unsigned short* S1B = (unsigned short*)take((size_t)NN * 128 * 2);
  unsigned short* T1B = (unsigned short*)take((size_t)NN * 128 * 2);
  unsigned short* w1tA = (unsigned short*)take(4 * 4096 * 2);
  unsigned short* w1mA = (unsigned short*)take(4 * 4096 * 2);
  unsigned short* w1tB = (unsigned short*)take(4 * 4096 * 2);
  unsigned short* w1mB = (unsigned short*)take(4 * 4096 * 2);
  unsigned short* w2pA = (unsigned short*)take(4 * 4096 * 2);
  unsigned short* w2pB = (unsigned short*)take(4 * 4096 * 2);
  unsigned short* wc1p = (unsigned short*)take(4 * 4096 * 2);
  unsigned short* wn1pt = (unsigned short*)take(8 * 4096 * 2);
  unsigned short* wn2pt = (unsigned short*)take(4 * 4096 * 2);
  unsigned short* wn1ps = (unsigned short*)take(8 * 4096 * 2);
  unsigned short* wn2ps = (unsigned short*)take(4 * 4096 * 2);
  int* cntT = (int*)take((size_t)NN * 4);
  int* cntS = (int*)take((size_t)NN * 4);
  const char* cntZeroStart = (const char*)cntT;
  const size_t cntZeroBytes = (size_t)((char*)cntS + NN * 4 - (char*)cntT);
  int* rowptrT = (int*)take((size_t)(NN + 1) * 4);
  int* rowptrS = (int*)take((size_t)(NN + 1) * 4);
  int* offT = (int*)take((size_t)NN * 4);
  int* offS = (int*)take((size_t)NN * 4);
  int* permT = (int*)take((size_t)NEDGE * 4);
  int* permS = (int*)take((size_t)NEDGE * 4);
  unsigned short* eBuf0 = (unsigned short*)take((size_t)NEDGE * 128 * 2);  // 81.9 MB
  const size_t need_single = off;
  unsigned short* eBuf1 = (unsigned short*)take((size_t)NEDGE * 128 * 2);
  const bool dual = (ws_size >= off);
  (void)need_single;

  hipMemsetAsync((void*)cntZeroStart, 0, cntZeroBytes, stream);

  PackJobs PJ;
  PJ.w[0] = w1_s2t;             PJ.o[0] = w1tA;  PJ.kreal[0] = 128; PJ.nk[0] = 4;
  PJ.w[1] = w1_s2t + 128 * 128; PJ.o[1] = w1mA;  PJ.kreal[1] = 128; PJ.nk[1] = 4;
  PJ.w[2] = w1_t2s;             PJ.o[2] = w1tB;  PJ.kreal[2] = 128; PJ.nk[2] = 4;
  PJ.w[3] = w1_t2s + 128 * 128; PJ.o[3] = w1mB;  PJ.kreal[3] = 128; PJ.nk[3] = 4;
  PJ.w[4] = w2_s2t;             PJ.o[4] = w2pA;  PJ.kreal[4] = 128; PJ.nk[4] = 4;
  PJ.w[5] = w2_t2s;             PJ.o[5] = w2pB;  PJ.kreal[5] = 128; PJ.nk[5] = 4;
  PJ.w[6] = wc1;                PJ.o[6] = wc1p;  PJ.kreal[6] = 128; PJ.nk[6] = 4;
  PJ.w[7] = wn1_t;              PJ.o[7] = wn1pt; PJ.kreal[7] = 256; PJ.nk[7] = 8;
  PJ.w[8] = wn2_t;              PJ.o[8] = wn2pt; PJ.kreal[8] = 128; PJ.nk[8] = 4;
  PJ.w[9] = wn1_s;              PJ.o[9] = wn1ps; PJ.kreal[9] = 256; PJ.nk[9] = 8;
  PJ.w[10] = wn2_s;             PJ.o[10] = wn2ps; PJ.kreal[10] = 128; PJ.nk[10] = 4;
  egnn_pack_all<<<dim3(16, 11), 256, 0, stream>>>(PJ);

  PreJobs PR;
  PR.x[0] = srcF; PR.w[0] = w1tA; PR.o[0] = S1A;
  PR.x[1] = tgtF; PR.w[1] = w1mA; PR.o[1] = T1A;
  PR.x[2] = srcF; PR.w[2] = w1tB; PR.o[2] = S1B;
  PR.x[3] = tgtF; PR.w[3] = w1mB; PR.o[3] = T1B;
  egnn_pre<<<dim3(313, 4), 256, 0, stream>>>(PR, NN);

  egnn_hist<<<NEDGE / 256, 256, 0, stream>>>(eTgt, eSrc, cntT, cntS);
  egnn_scan<<<2, 1024, 0, stream>>>(cntT, rowptrT, offT, cntS, rowptrS, offS, NN);
  egnn_scatter<<<NEDGE / 256, 256, 0, stream>>>(eTgt, eSrc, offT, offS, permT, permS);

  float* outSrc = (float*)d_out;
  float* outTgt = outSrc + (size_t)NN * 128;
  float* outSC  = outTgt + (size_t)NN * 128;
  float* outTC  = outSC + (size_t)NN * 3;

  EdgePtrs EP;
  EP.perm[0] = permT; EP.perm[1] = permS;
  EP.eOut[0] = eBuf0; EP.eOut[1] = dual ? eBuf1 : eBuf0;

  if (dual) {
    egnn_edge<<<dim3(NEDGE / 128, 2), 256, 0, stream>>>(
        S1A, T1A, S1B, T1B, srcC, tgtC, eSrc, eTgt,
        w1_s2t, b1_s2t, w1_t2s, b1_t2s,
        w2pA, b2_s2t, wg_s2t, bg_s2t,
        w2pB, b2_t2s, wg_t2s, bg_t2s,
        wc1p, bc1, wc2, EP, wtBuf, /*dirBase=*/-1);
    egnn_agg<<<NN / 4, 256, 0, stream>>>(eBuf0, rowptrT, aggA);
    egnn_coord<<<(NN + 255) / 256, 256, 0, stream>>>(
        srcC, tgtC, wtBuf, rowptrT, outSC, outTC);
    egnn_agg<<<NN / 4, 256, 0, stream>>>(eBuf1, rowptrS, aggB);
  } else {
    egnn_edge<<<NEDGE / 128, 256, 0, stream>>>(
        S1A, T1A, S1B, T1B, srcC, tgtC, eSrc, eTgt,
        w1_s2t, b1_s2t, w1_t2s, b1_t2s,
        w2pA, b2_s2t, wg_s2t, bg_s2t,
        w2pB, b2_t2s, wg_t2s, bg_t2s,
        wc1p, bc1, wc2, EP, wtBuf, /*dirBase=*/0);
    egnn_agg<<<NN / 4, 256, 0, stream>>>(eBuf0, rowptrT, aggA);
    egnn_coord<<<(NN + 255) / 256, 256, 0, stream>>>(
        srcC, tgtC, wtBuf, rowptrT, outSC, outTC);
    egnn_edge<<<NEDGE / 128, 256, 0, stream>>>(
        S1A, T1A, S1B, T1B, srcC, tgtC, eSrc, eTgt,
        w1_s2t, b1_s2t, w1_t2s, b1_t2s,
        w2pA, b2_s2t, wg_s2t, bg_s2t,
        w2pB, b2_t2s, wg_t2s, bg_t2s,
        wc1p, bc1, wc2, EP, wtBuf, /*dirBase=*/1);
    egnn_agg<<<NN / 4, 256, 0, stream>>>(eBuf0, rowptrS, aggB);
  }

  egnn_node<<<(NN + TILE_N - 1) / TILE_N, 256, 0, stream>>>(
      tgtF, aggA, wn1pt, bn1_t, wn2pt, bn2_t, outTgt, NN);
  egnn_node<<<(NN + TILE_N - 1) / TILE_N, 256, 0, stream>>>(
      srcF, aggB, wn1ps, bn1_s, wn2ps, bn2_s, outSrc, NN);
}

// Round 5
// 374.597 us; speedup vs baseline: 2.2566x; 1.1683x over previous
//
#include <hip/hip_runtime.h>

#define NN 20000
#define NEDGE 320000
#define COORD_MAX 10.0f

#define LDH 136    // ushort stride (272B, 16B-aligned)
#define TILE_N 64
#define LDN  264   // node kernel input stride (K=256)

typedef __attribute__((ext_vector_type(4))) float f32x4;
typedef __attribute__((ext_vector_type(8))) short short8;
typedef __attribute__((ext_vector_type(8))) __bf16 bf16x8;

static __device__ __forceinline__ f32x4 mfma16(short8 a, short8 b, f32x4 c) {
  return __builtin_amdgcn_mfma_f32_16x16x32_bf16(
      __builtin_bit_cast(bf16x8, a), __builtin_bit_cast(bf16x8, b), c, 0, 0, 0);
}
static __device__ __forceinline__ unsigned short f2bf(float f) {
  unsigned u = __builtin_bit_cast(unsigned, f);
  u += 0x7FFFu + ((u >> 16) & 1u);
  return (unsigned short)(u >> 16);
}
static __device__ __forceinline__ float bf2f(unsigned short u) {
  unsigned x = ((unsigned)u) << 16;
  return __builtin_bit_cast(float, x);
}
// packed f32x2 -> bf16x2 (RNE), 1 VALU op (gfx950)
static __device__ __forceinline__ unsigned cvtpk(float lo, float hi) {
  unsigned r;
  asm("v_cvt_pk_bf16_f32 %0, %1, %2" : "=v"(r) : "v"(lo), "v"(hi));
  return r;
}
// fast sigmoid: v_rcp instead of full-precision divide sequence
static __device__ __forceinline__ float sigm(float x) {
  return __builtin_amdgcn_rcpf(1.f + __expf(-x));
}
static __device__ __forceinline__ float silu_(float x) { return x * sigm(x); }

// ---------------------------------------------------------------------------
// Weight pack: fp32 [Kreal][128] row-major -> bf16 MFMA B-fragment order.
// ---------------------------------------------------------------------------
struct PackJobs {
  const float* w[11];
  unsigned short* o[11];
  int kreal[11];
  int nk[11];
};

__global__ void egnn_pack_all(PackJobs J) {
  const int job = blockIdx.y;
  const int nk = J.nk[job];
  const int idx = blockIdx.x * 256 + threadIdx.x;
  if (idx >= nk * 512) return;
  const float* w = J.w[job];
  const int kreal = J.kreal[job];
  const int lane = idx & 63;
  const int ct = (idx >> 6) & 7;
  const int kstep = idx >> 9;
  const int col = ct * 16 + (lane & 15);
  const int k0 = kstep * 32 + (lane >> 4) * 8;
  union { short8 s; unsigned short u[8]; } t;
#pragma unroll
  for (int j = 0; j < 8; ++j) {
    int k = k0 + j;
    t.u[j] = (k < kreal) ? f2bf(w[(size_t)k * 128 + col]) : (unsigned short)0;
  }
  reinterpret_cast<short8*>(J.o[job])[idx] = t.s;
}

// ---------------------------------------------------------------------------
// Precompute S1/T1 = X @ W (K=128), output bf16 [N][128]. 4 jobs via blockIdx.y.
// ---------------------------------------------------------------------------
struct PreJobs {
  const float* x[4];
  const unsigned short* w[4];
  unsigned short* o[4];
};

__global__ __launch_bounds__(256, 2) void egnn_pre(PreJobs J, int N) {
  __shared__ __align__(16) unsigned short sX[64 * LDH];
  const int job = blockIdx.y;
  const float* X = J.x[job];
  const unsigned short* W = J.w[job];
  unsigned short* O = J.o[job];
  const int n0 = blockIdx.x * 64;
  const int tid = threadIdx.x;

  for (int s = tid; s < 64 * 32; s += 256) {
    const int row = s >> 5;
    const int c4 = (s & 31) * 4;
    const int node = n0 + row;
    float4 v = {0.f, 0.f, 0.f, 0.f};
    if (node < N) v = reinterpret_cast<const float4*>(X + (size_t)node * 128)[s & 31];
    *reinterpret_cast<uint2*>(&sX[row * LDH + c4]) =
        uint2{cvtpk(v.x, v.y), cvtpk(v.z, v.w)};
  }
  __syncthreads();

  const int lane = tid & 63, wid = tid >> 6;
  const int r16 = lane & 15, g4 = lane >> 4;
  const int rowBase = wid * 16;

  f32x4 acc[8];
#pragma unroll
  for (int ct = 0; ct < 8; ++ct) acc[ct] = f32x4{0.f, 0.f, 0.f, 0.f};
#pragma unroll
  for (int ks = 0; ks < 4; ++ks) {
    const short8 a = *reinterpret_cast<const short8*>(
        &sX[(rowBase + r16) * LDH + ks * 32 + g4 * 8]);
#pragma unroll
    for (int ct = 0; ct < 8; ++ct) {
      const short8 b = *reinterpret_cast<const short8*>(
          W + ((size_t)(ks * 8 + ct) * 64 + lane) * 8);
      acc[ct] = mfma16(a, b, acc[ct]);
    }
  }
#pragma unroll
  for (int ct = 0; ct < 8; ++ct) {
    const int col = ct * 16 + r16;
#pragma unroll
    for (int r = 0; r < 4; ++r) {
      const int node = n0 + rowBase + g4 * 4 + r;
      if (node < N) O[(size_t)node * 128 + col] = f2bf(acc[ct][r]);
    }
  }
}

// ---------------------------------------------------------------------------
// Counting sort by tgt and by src.
// ---------------------------------------------------------------------------
__global__ void egnn_hist(const int* __restrict__ eTgt, const int* __restrict__ eSrc,
                          int* __restrict__ cntT, int* __restrict__ cntS) {
  const int e = blockIdx.x * 256 + threadIdx.x;
  if (e < NEDGE) {
    atomicAdd(&cntT[eTgt[e]], 1);
    atomicAdd(&cntS[eSrc[e]], 1);
  }
}

__global__ __launch_bounds__(1024) void egnn_scan(
    const int* __restrict__ c0, int* __restrict__ r0, int* __restrict__ o0,
    const int* __restrict__ c1, int* __restrict__ r1, int* __restrict__ o1, int n) {
  const int* cnt = blockIdx.x ? c1 : c0;
  int* rp = blockIdx.x ? r1 : r0;
  int* oc = blockIdx.x ? o1 : o0;
  __shared__ int sums[1024];
  const int tid = threadIdx.x;
  const int chunk = (n + 1023) / 1024;
  const int i0 = tid * chunk;
  int local = 0;
  for (int k = 0; k < chunk; ++k) {
    const int i = i0 + k;
    if (i < n) local += cnt[i];
  }
  sums[tid] = local;
  __syncthreads();
  for (int s = 1; s < 1024; s <<= 1) {
    int v = (tid >= s) ? sums[tid - s] : 0;
    __syncthreads();
    sums[tid] += v;
    __syncthreads();
  }
  int run = (tid == 0) ? 0 : sums[tid - 1];
  for (int k = 0; k < chunk; ++k) {
    const int i = i0 + k;
    if (i < n) { rp[i] = run; oc[i] = run; run += cnt[i]; }
  }
  if (tid == 1023) rp[n] = sums[1023];
}

__global__ void egnn_scatter(const int* __restrict__ eTgt, const int* __restrict__ eSrc,
                             int* __restrict__ offT, int* __restrict__ offS,
                             int* __restrict__ permT, int* __restrict__ permS) {
  const int e = blockIdx.x * 256 + threadIdx.x;
  if (e < NEDGE) {
    permT[atomicAdd(&offT[eTgt[e]], 1)] = e;
    permS[atomicAdd(&offS[eSrc[e]], 1)] = e;
  }
}

// ---------------------------------------------------------------------------
// Fused edge kernel, sorted order. 128 edges/block, 4 waves x 32 edges.
// ---------------------------------------------------------------------------
struct EdgePtrs {
  const int* perm[2];
  unsigned short* eOut[2];
};

__global__ __launch_bounds__(256, 4) void egnn_edge(
    const unsigned short* __restrict__ S1A, const unsigned short* __restrict__ T1A,
    const unsigned short* __restrict__ S1B, const unsigned short* __restrict__ T1B,
    const float* __restrict__ srcC, const float* __restrict__ tgtC,
    const int* __restrict__ eSrc, const int* __restrict__ eTgt,
    const float* __restrict__ w1A, const float* __restrict__ b1A,
    const float* __restrict__ w1B, const float* __restrict__ b1B,
    const unsigned short* __restrict__ w2pA, const float* __restrict__ b2A,
    const float* __restrict__ wgA, const float* __restrict__ bgA,
    const unsigned short* __restrict__ w2pB, const float* __restrict__ b2B,
    const float* __restrict__ wgB, const float* __restrict__ bgB,
    const unsigned short* __restrict__ wc1p, const float* __restrict__ bc1,
    const float* __restrict__ wc2,
    EdgePtrs EP, float* __restrict__ wtBuf, int dirBase)
{
  __shared__ __align__(16) unsigned short sH[4][32 * LDH];  // 34816 B
  __shared__ float sCD[128 * 3];
  __shared__ float sRad[128];
  __shared__ int sS[128];
  __shared__ int sT[128];

  const int dir = (dirBase >= 0) ? dirBase : (int)blockIdx.y;
  const int tid = threadIdx.x;
  const int j0 = blockIdx.x * 128;
  const int* __restrict__ perm = EP.perm[dir];
  unsigned short* __restrict__ eOut = EP.eOut[dir];

  if (tid < 128) {
    const int e = perm[j0 + tid];
    const int s = eSrc[e], t = eTgt[e];
    sS[tid] = s; sT[tid] = t;
    const float dx = tgtC[t * 3 + 0] - srcC[s * 3 + 0];
    const float dy = tgtC[t * 3 + 1] - srcC[s * 3 + 1];
    const float dz = tgtC[t * 3 + 2] - srcC[s * 3 + 2];
    sCD[tid * 3 + 0] = dx; sCD[tid * 3 + 1] = dy; sCD[tid * 3 + 2] = dz;
    sRad[tid] = dx * dx + dy * dy + dz * dz;
  }
  __syncthreads();

  const int lane = tid & 63, wid = tid >> 6;
  const int r16 = lane & 15, g4 = lane >> 4;
  const int we = wid * 32;
  const int h32 = lane >> 5;
  const int c4 = (lane & 31) * 4;

  const unsigned short* S1 = dir ? S1B : S1A;
  const unsigned short* T1 = dir ? T1B : T1A;
  const float* w1 = dir ? w1B : w1A;
  const float* b1 = dir ? b1B : b1A;
  const float4 wr = *reinterpret_cast<const float4*>(w1 + 256 * 128 + c4);
  const float4 bb = *reinterpret_cast<const float4*>(b1 + c4);

  unsigned short* hT = sH[wid];

  // ---- build h-tile: h = silu(S1[s] + T1[t] + rad*wr + bb), bf16 -> LDS
#pragma unroll 8
  for (int i = 0; i < 16; ++i) {
    const int row = 2 * i + h32;
    const int e = we + row;
    const int s = sS[e], t = sT[e];
    const float rad = sRad[e];
    const ushort4 a = *reinterpret_cast<const ushort4*>(S1 + (size_t)s * 128 + c4);
    const ushort4 b = *reinterpret_cast<const ushort4*>(T1 + (size_t)t * 128 + c4);
    const float f0 = silu_(bf2f(a.x) + bf2f(b.x) + rad * wr.x + bb.x);
    const float f1 = silu_(bf2f(a.y) + bf2f(b.y) + rad * wr.y + bb.y);
    const float f2 = silu_(bf2f(a.z) + bf2f(b.z) + rad * wr.z + bb.z);
    const float f3 = silu_(bf2f(a.w) + bf2f(b.w) + rad * wr.w + bb.w);
    *reinterpret_cast<uint2*>(&hT[row * LDH + c4]) =
        uint2{cvtpk(f0, f1), cvtpk(f2, f3)};
  }

  // ---- GEMM2: 2 row-tiles x [16x128] @ [128x128]
  const unsigned short* w2p = dir ? w2pB : w2pA;
  f32x4 acc[2][8];
#pragma unroll
  for (int rt = 0; rt < 2; ++rt)
#pragma unroll
    for (int ct = 0; ct < 8; ++ct) acc[rt][ct] = f32x4{0.f, 0.f, 0.f, 0.f};
#pragma unroll
  for (int ks = 0; ks < 4; ++ks) {
    short8 a[2];
#pragma unroll
    for (int rt = 0; rt < 2; ++rt)
      a[rt] = *reinterpret_cast<const short8*>(
          &hT[(rt * 16 + r16) * LDH + ks * 32 + g4 * 8]);
#pragma unroll
    for (int ct = 0; ct < 8; ++ct) {
      const short8 b = *reinterpret_cast<const short8*>(
          w2p + ((size_t)(ks * 8 + ct) * 64 + lane) * 8);
#pragma unroll
      for (int rt = 0; rt < 2; ++rt) acc[rt][ct] = mfma16(a[rt], b, acc[rt][ct]);
    }
  }

  // ---- bias + SiLU + gate
  const float* b2 = dir ? b2B : b2A;
  const float* wg = dir ? wgB : wgA;
  const float bg = dir ? bgB[0] : bgA[0];
  float part[2][4];
#pragma unroll
  for (int rt = 0; rt < 2; ++rt)
#pragma unroll
    for (int r = 0; r < 4; ++r) part[rt][r] = 0.f;
#pragma unroll
  for (int ct = 0; ct < 8; ++ct) {
    const float b2v = b2[ct * 16 + r16];
    const float wgv = wg[ct * 16 + r16];
#pragma unroll
    for (int rt = 0; rt < 2; ++rt)
#pragma unroll
      for (int r = 0; r < 4; ++r) {
        const float e = silu_(acc[rt][ct][r] + b2v);
        acc[rt][ct][r] = e;
        part[rt][r] += e * wgv;
      }
  }
#pragma unroll
  for (int m = 1; m < 16; m <<= 1)
#pragma unroll
    for (int rt = 0; rt < 2; ++rt)
#pragma unroll
      for (int r = 0; r < 4; ++r) part[rt][r] += __shfl_xor(part[rt][r], m, 64);
#pragma unroll
  for (int rt = 0; rt < 2; ++rt)
#pragma unroll
    for (int r = 0; r < 4; ++r) {
      const float gate = sigm(part[rt][r] + bg);
#pragma unroll
      for (int ct = 0; ct < 8; ++ct) acc[rt][ct][r] *= gate;
    }

  // ---- stash gated e (bf16) into LDS (transpose for writeout + coord A-frag)
#pragma unroll
  for (int rt = 0; rt < 2; ++rt)
#pragma unroll
    for (int ct = 0; ct < 8; ++ct)
#pragma unroll
      for (int r = 0; r < 4; ++r)
        hT[(rt * 16 + g4 * 4 + r) * LDH + ct * 16 + r16] = f2bf(acc[rt][ct][r]);

  // ---- coalesced write of the wave's 32 e-rows at SORTED positions
#pragma unroll 4
  for (int it = 0; it < 16; ++it) {
    const int row = it * 2 + h32;
    *reinterpret_cast<ushort4*>(eOut + (size_t)(j0 + we + row) * 128 + c4) =
        *reinterpret_cast<const ushort4*>(&hT[row * LDH + c4]);
  }

  if (dir == 0) {
    // ---- coord GEMM on gated e_s2t
    f32x4 ac[2][8];
#pragma unroll
    for (int rt = 0; rt < 2; ++rt)
#pragma unroll
      for (int ct = 0; ct < 8; ++ct) ac[rt][ct] = f32x4{0.f, 0.f, 0.f, 0.f};
#pragma unroll
    for (int ks = 0; ks < 4; ++ks) {
      short8 a[2];
#pragma unroll
      for (int rt = 0; rt < 2; ++rt)
        a[rt] = *reinterpret_cast<const short8*>(
            &hT[(rt * 16 + r16) * LDH + ks * 32 + g4 * 8]);
#pragma unroll
      for (int ct = 0; ct < 8; ++ct) {
        const short8 b = *reinterpret_cast<const short8*>(
            wc1p + ((size_t)(ks * 8 + ct) * 64 + lane) * 8);
#pragma unroll
        for (int rt = 0; rt < 2; ++rt) ac[rt][ct] = mfma16(a[rt], b, ac[rt][ct]);
      }
    }
    float pc[2][4];
#pragma unroll
    for (int rt = 0; rt < 2; ++rt)
#pragma unroll
      for (int r = 0; r < 4; ++r) pc[rt][r] = 0.f;
#pragma unroll
    for (int ct = 0; ct < 8; ++ct) {
      const float bcv = bc1[ct * 16 + r16];
      const float w2v = wc2[ct * 16 + r16];
#pragma unroll
      for (int rt = 0; rt < 2; ++rt)
#pragma unroll
        for (int r = 0; r < 4; ++r)
          pc[rt][r] += silu_(ac[rt][ct][r] + bcv) * w2v;
    }
#pragma unroll
    for (int m = 1; m < 16; m <<= 1)
#pragma unroll
      for (int rt = 0; rt < 2; ++rt)
#pragma unroll
        for (int r = 0; r < 4; ++r) pc[rt][r] += __shfl_xor(pc[rt][r], m, 64);

    // per-edge weighted coord diff -> wtBuf (sorted position), no atomics
#pragma unroll
    for (int rt = 0; rt < 2; ++rt)
#pragma unroll
      for (int r = 0; r < 4; ++r) {
        if (r16 == 0) {
          const int el = we + rt * 16 + g4 * 4 + r;
          const float p = pc[rt][r];
          const float4 w = {sCD[el * 3 + 0] * p, sCD[el * 3 + 1] * p,
                            sCD[el * 3 + 2] * p, 0.f};
          *reinterpret_cast<float4*>(wtBuf + (size_t)(j0 + el) * 4) = w;
        }
      }
  }
}

// ---------------------------------------------------------------------------
// Coord finalize: segmented sum of wtBuf by tgt (contiguous), /max(deg,1),
// clip, add; also copy src coords.
// ---------------------------------------------------------------------------
__global__ void egnn_coord(const float* __restrict__ srcC, const float* __restrict__ tgtC,
                           const float* __restrict__ wt, const int* __restrict__ rp,
                           float* __restrict__ outSC, float* __restrict__ outTC) {
  const int n = blockIdx.x * 256 + threadIdx.x;
  if (n >= NN) return;
  outSC[n * 3 + 0] = srcC[n * 3 + 0];
  outSC[n * 3 + 1] = srcC[n * 3 + 1];
  outSC[n * 3 + 2] = srcC[n * 3 + 2];
  const int j0 = rp[n], j1 = rp[n + 1];
  float ax = 0.f, ay = 0.f, az = 0.f;
  for (int j = j0; j < j1; ++j) {
    const float4 v = *reinterpret_cast<const float4*>(wt + (size_t)j * 4);
    ax += v.x; ay += v.y; az += v.z;
  }
  const float c = fmaxf((float)(j1 - j0), 1.f);
  ax = fminf(fmaxf(ax / c, -COORD_MAX), COORD_MAX);
  ay = fminf(fmaxf(ay / c, -COORD_MAX), COORD_MAX);
  az = fminf(fmaxf(az / c, -COORD_MAX), COORD_MAX);
  outTC[n * 3 + 0] = tgtC[n * 3 + 0] + ax;
  outTC[n * 3 + 1] = tgtC[n * 3 + 1] + ay;
  outTC[n * 3 + 2] = tgtC[n * 3 + 2] + az;
}

// ---------------------------------------------------------------------------
// Node kernel with FUSED segmented aggregation:
// agg[n] = sum of contiguous sorted eBuf rows rp[n]..rp[n+1) (fp32, in regs)
// out = feat + (silu([feat|agg] @ wn1 + bn1) @ wn2 + bn2).  2 jobs (grid.y).
// ---------------------------------------------------------------------------
struct NodeJobs {
  const float* feat[2];
  const unsigned short* eBuf[2];
  const int* rp[2];
  const unsigned short* w1p[2];
  const float* b1[2];
  const unsigned short* w2p[2];
  const float* b2[2];
  float* outp[2];
};

__global__ __launch_bounds__(256, 2) void egnn_node(NodeJobs J, int N, int jobSel) {
  __shared__ __align__(16) unsigned short sIn[TILE_N * LDN];
  __shared__ __align__(16) unsigned short sH2[TILE_N * LDH];
  const int job = (jobSel >= 0) ? jobSel : (int)blockIdx.y;
  const float* __restrict__ feat = J.feat[job];
  const unsigned short* __restrict__ eBuf = J.eBuf[job];
  const int* __restrict__ rp = J.rp[job];
  const unsigned short* __restrict__ w1p = J.w1p[job];
  const float* __restrict__ b1 = J.b1[job];
  const unsigned short* __restrict__ w2p = J.w2p[job];
  const float* __restrict__ b2 = J.b2[job];
  float* __restrict__ outp = J.outp[job];

  const int tid = threadIdx.x;
  const int n0 = blockIdx.x * TILE_N;
  const int lane = tid & 63;
  const int wid = tid >> 6;

  // ---- stage feat half (cols 0..127), bf16
  for (int s = tid; s < 64 * 32; s += 256) {
    const int row = s >> 5;
    const int c4 = (s & 31) * 4;
    const int node = n0 + row;
    float4 v = {0.f, 0.f, 0.f, 0.f};
    if (node < N) v = reinterpret_cast<const float4*>(feat + (size_t)node * 128)[s & 31];
    *reinterpret_cast<uint2*>(&sIn[row * LDN + c4]) =
        uint2{cvtpk(v.x, v.y), cvtpk(v.z, v.w)};
  }

  // ---- stage agg half (cols 128..255): fused contiguous segmented sum
  {
    const int nbase = n0 + wid * 16;
#pragma unroll 1
    for (int i = 0; i < 16; ++i) {
      const int n = nbase + i;
      float a0 = 0.f, a1 = 0.f;
      if (n < N) {
        const int j0 = rp[n], j1 = rp[n + 1];
        const unsigned short* p = eBuf + (size_t)j0 * 128 + lane * 2;
        int m = j1 - j0;
        for (; m >= 4; m -= 4) {
          const ushort2 v0 = *reinterpret_cast<const ushort2*>(p);
          const ushort2 v1 = *reinterpret_cast<const ushort2*>(p + 128);
          const ushort2 v2 = *reinterpret_cast<const ushort2*>(p + 256);
          const ushort2 v3 = *reinterpret_cast<const ushort2*>(p + 384);
          p += 512;
          a0 += bf2f(v0.x) + bf2f(v1.x) + bf2f(v2.x) + bf2f(v3.x);
          a1 += bf2f(v0.y) + bf2f(v1.y) + bf2f(v2.y) + bf2f(v3.y);
        }
        for (; m > 0; --m) {
          const ushort2 v = *reinterpret_cast<const ushort2*>(p);
          p += 128;
          a0 += bf2f(v.x); a1 += bf2f(v.y);
        }
      }
      *reinterpret_cast<unsigned*>(&sIn[(wid * 16 + i) * LDN + 128 + lane * 2]) =
          cvtpk(a0, a1);
    }
  }
  __syncthreads();

  const int rowBase = wid * 16;
  const int r16 = lane & 15;
  const int g4 = lane >> 4;

  f32x4 acc[8];
#pragma unroll
  for (int ct = 0; ct < 8; ++ct) acc[ct] = f32x4{0.f, 0.f, 0.f, 0.f};
#pragma unroll
  for (int ks = 0; ks < 8; ++ks) {
    const short8 a = *reinterpret_cast<const short8*>(
        &sIn[(rowBase + r16) * LDN + ks * 32 + g4 * 8]);
#pragma unroll
    for (int ct = 0; ct < 8; ++ct) {
      const short8 b = *reinterpret_cast<const short8*>(
          w1p + ((size_t)(ks * 8 + ct) * 64 + lane) * 8);
      acc[ct] = mfma16(a, b, acc[ct]);
    }
  }
#pragma unroll
  for (int ct = 0; ct < 8; ++ct) {
    const int col = ct * 16 + r16;
    const float bias = b1[col];
#pragma unroll
    for (int r = 0; r < 4; ++r) {
      const float h = silu_(acc[ct][r] + bias);
      sH2[(rowBase + g4 * 4 + r) * LDH + col] = f2bf(h);
    }
  }

  f32x4 acc2[8];
#pragma unroll
  for (int ct = 0; ct < 8; ++ct) acc2[ct] = f32x4{0.f, 0.f, 0.f, 0.f};
#pragma unroll
  for (int ks = 0; ks < 4; ++ks) {
    const short8 a = *reinterpret_cast<const short8*>(
        &sH2[(rowBase + r16) * LDH + ks * 32 + g4 * 8]);
#pragma unroll
    for (int ct = 0; ct < 8; ++ct) {
      const short8 b = *reinterpret_cast<const short8*>(
          w2p + ((size_t)(ks * 8 + ct) * 64 + lane) * 8);
      acc2[ct] = mfma16(a, b, acc2[ct]);
    }
  }

#pragma unroll
  for (int ct = 0; ct < 8; ++ct) {
    const int col = ct * 16 + r16;
    const float bias = b2[col];
#pragma unroll
    for (int r = 0; r < 4; ++r) {
      const int node = n0 + rowBase + g4 * 4 + r;
      if (node < N)
        outp[(size_t)node * 128 + col] = feat[(size_t)node * 128 + col] + acc2[ct][r] + bias;
    }
  }
}

extern "C" void kernel_launch(void* const* d_in, const int* in_sizes, int n_in,
                              void* d_out, int out_size, void* d_ws, size_t ws_size,
                              hipStream_t stream) {
  const float* srcF = (const float*)d_in[0];
  const float* tgtF = (const float*)d_in[1];
  const float* srcC = (const float*)d_in[2];
  const float* tgtC = (const float*)d_in[3];
  const int* eSrc = (const int*)d_in[4];
  const int* eTgt = (const int*)d_in[5];
  const float* w1_s2t = (const float*)d_in[6];
  const float* b1_s2t = (const float*)d_in[7];
  const float* w2_s2t = (const float*)d_in[8];
  const float* b2_s2t = (const float*)d_in[9];
  const float* w1_t2s = (const float*)d_in[10];
  const float* b1_t2s = (const float*)d_in[11];
  const float* w2_t2s = (const float*)d_in[12];
  const float* b2_t2s = (const float*)d_in[13];
  const float* wg_s2t = (const float*)d_in[14];
  const float* bg_s2t = (const float*)d_in[15];
  const float* wg_t2s = (const float*)d_in[16];
  const float* bg_t2s = (const float*)d_in[17];
  const float* wc1 = (const float*)d_in[18];
  const float* bc1 = (const float*)d_in[19];
  const float* wc2 = (const float*)d_in[20];
  const float* wn1_t = (const float*)d_in[21];
  const float* bn1_t = (const float*)d_in[22];
  const float* wn2_t = (const float*)d_in[23];
  const float* bn2_t = (const float*)d_in[24];
  const float* wn1_s = (const float*)d_in[25];
  const float* bn1_s = (const float*)d_in[26];
  const float* wn2_s = (const float*)d_in[27];
  const float* bn2_s = (const float*)d_in[28];

  char* ws = (char*)d_ws;
  size_t off = 0;
  auto take = [&](size_t bytes) -> char* {
    char* p = ws + off;
    off = (off + bytes + 255) & ~(size_t)255;
    return p;
  };
  float* wtBuf = (float*)take((size_t)NEDGE * 4 * 4);          // 5.12 MB
  unsigned short* S1A = (unsigned short*)take((size_t)NN * 128 * 2);
  unsigned short* T1A = (unsigned short*)take((size_t)NN * 128 * 2);
  unsigned short* S1B = (unsigned short*)take((size_t)NN * 128 * 2);
  unsigned short* T1B = (unsigned short*)take((size_t)NN * 128 * 2);
  unsigned short* w1tA = (unsigned short*)take(4 * 4096 * 2);
  unsigned short* w1mA = (unsigned short*)take(4 * 4096 * 2);
  unsigned short* w1tB = (unsigned short*)take(4 * 4096 * 2);
  unsigned short* w1mB = (unsigned short*)take(4 * 4096 * 2);
  unsigned short* w2pA = (unsigned short*)take(4 * 4096 * 2);
  unsigned short* w2pB = (unsigned short*)take(4 * 4096 * 2);
  unsigned short* wc1p = (unsigned short*)take(4 * 4096 * 2);
  unsigned short* wn1pt = (unsigned short*)take(8 * 4096 * 2);
  unsigned short* wn2pt = (unsigned short*)take(4 * 4096 * 2);
  unsigned short* wn1ps = (unsigned short*)take(8 * 4096 * 2);
  unsigned short* wn2ps = (unsigned short*)take(4 * 4096 * 2);
  int* cntT = (int*)take((size_t)NN * 4);
  int* cntS = (int*)take((size_t)NN * 4);
  const char* cntZeroStart = (const char*)cntT;
  const size_t cntZeroBytes = (size_t)((char*)cntS + NN * 4 - (char*)cntT);
  int* rowptrT = (int*)take((size_t)(NN + 1) * 4);
  int* rowptrS = (int*)take((size_t)(NN + 1) * 4);
  int* offT = (int*)take((size_t)NN * 4);
  int* offS = (int*)take((size_t)NN * 4);
  int* permT = (int*)take((size_t)NEDGE * 4);
  int* permS = (int*)take((size_t)NEDGE * 4);
  unsigned short* eBuf0 = (unsigned short*)take((size_t)NEDGE * 128 * 2);  // 81.9 MB
  unsigned short* eBuf1 = (unsigned short*)take((size_t)NEDGE * 128 * 2);
  const bool dual = (ws_size >= off);

  hipMemsetAsync((void*)cntZeroStart, 0, cntZeroBytes, stream);

  PackJobs PJ;
  PJ.w[0] = w1_s2t;             PJ.o[0] = w1tA;  PJ.kreal[0] = 128; PJ.nk[0] = 4;
  PJ.w[1] = w1_s2t + 128 * 128; PJ.o[1] = w1mA;  PJ.kreal[1] = 128; PJ.nk[1] = 4;
  PJ.w[2] = w1_t2s;             PJ.o[2] = w1tB;  PJ.kreal[2] = 128; PJ.nk[2] = 4;
  PJ.w[3] = w1_t2s + 128 * 128; PJ.o[3] = w1mB;  PJ.kreal[3] = 128; PJ.nk[3] = 4;
  PJ.w[4] = w2_s2t;             PJ.o[4] = w2pA;  PJ.kreal[4] = 128; PJ.nk[4] = 4;
  PJ.w[5] = w2_t2s;             PJ.o[5] = w2pB;  PJ.kreal[5] = 128; PJ.nk[5] = 4;
  PJ.w[6] = wc1;                PJ.o[6] = wc1p;  PJ.kreal[6] = 128; PJ.nk[6] = 4;
  PJ.w[7] = wn1_t;              PJ.o[7] = wn1pt; PJ.kreal[7] = 256; PJ.nk[7] = 8;
  PJ.w[8] = wn2_t;              PJ.o[8] = wn2pt; PJ.kreal[8] = 128; PJ.nk[8] = 4;
  PJ.w[9] = wn1_s;              PJ.o[9] = wn1ps; PJ.kreal[9] = 256; PJ.nk[9] = 8;
  PJ.w[10] = wn2_s;             PJ.o[10] = wn2ps; PJ.kreal[10] = 128; PJ.nk[10] = 4;
  egnn_pack_all<<<dim3(16, 11), 256, 0, stream>>>(PJ);

  PreJobs PR;
  PR.x[0] = srcF; PR.w[0] = w1tA; PR.o[0] = S1A;
  PR.x[1] = tgtF; PR.w[1] = w1mA; PR.o[1] = T1A;
  PR.x[2] = srcF; PR.w[2] = w1tB; PR.o[2] = S1B;
  PR.x[3] = tgtF; PR.w[3] = w1mB; PR.o[3] = T1B;
  egnn_pre<<<dim3(313, 4), 256, 0, stream>>>(PR, NN);

  egnn_hist<<<NEDGE / 256, 256, 0, stream>>>(eTgt, eSrc, cntT, cntS);
  egnn_scan<<<2, 1024, 0, stream>>>(cntT, rowptrT, offT, cntS, rowptrS, offS, NN);
  egnn_scatter<<<NEDGE / 256, 256, 0, stream>>>(eTgt, eSrc, offT, offS, permT, permS);

  float* outSrc = (float*)d_out;
  float* outTgt = outSrc + (size_t)NN * 128;
  float* outSC  = outTgt + (size_t)NN * 128;
  float* outTC  = outSC + (size_t)NN * 3;

  EdgePtrs EP;
  EP.perm[0] = permT; EP.perm[1] = permS;
  EP.eOut[0] = eBuf0; EP.eOut[1] = dual ? eBuf1 : eBuf0;

  NodeJobs NJ;
  NJ.feat[0] = tgtF; NJ.eBuf[0] = eBuf0; NJ.rp[0] = rowptrT;
  NJ.w1p[0] = wn1pt; NJ.b1[0] = bn1_t; NJ.w2p[0] = wn2pt; NJ.b2[0] = bn2_t;
  NJ.outp[0] = outTgt;
  NJ.feat[1] = srcF; NJ.eBuf[1] = dual ? eBuf1 : eBuf0; NJ.rp[1] = rowptrS;
  NJ.w1p[1] = wn1ps; NJ.b1[1] = bn1_s; NJ.w2p[1] = wn2ps; NJ.b2[1] = bn2_s;
  NJ.outp[1] = outSrc;

  const int nodeBlocks = (NN + TILE_N - 1) / TILE_N;

  if (dual) {
    egnn_edge<<<dim3(NEDGE / 128, 2), 256, 0, stream>>>(
        S1A, T1A, S1B, T1B, srcC, tgtC, eSrc, eTgt,
        w1_s2t, b1_s2t, w1_t2s, b1_t2s,
        w2pA, b2_s2t, wg_s2t, bg_s2t,
        w2pB, b2_t2s, wg_t2s, bg_t2s,
        wc1p, bc1, wc2, EP, wtBuf, /*dirBase=*/-1);
    egnn_coord<<<(NN + 255) / 256, 256, 0, stream>>>(
        srcC, tgtC, wtBuf, rowptrT, outSC, outTC);
    egnn_node<<<dim3(nodeBlocks, 2), 256, 0, stream>>>(NJ, NN, -1);
  } else {
    egnn_edge<<<NEDGE / 128, 256, 0, stream>>>(
        S1A, T1A, S1B, T1B, srcC, tgtC, eSrc, eTgt,
        w1_s2t, b1_s2t, w1_t2s, b1_t2s,
        w2pA, b2_s2t, wg_s2t, bg_s2t,
        w2pB, b2_t2s, wg_t2s, bg_t2s,
        wc1p, bc1, wc2, EP, wtBuf, /*dirBase=*/0);
    egnn_coord<<<(NN + 255) / 256, 256, 0, stream>>>(
        srcC, tgtC, wtBuf, rowptrT, outSC, outTC);
    egnn_node<<<nodeBlocks, 256, 0, stream>>>(NJ, NN, 0);
    egnn_edge<<<NEDGE / 128, 256, 0, stream>>>(
        S1A, T1A, S1B, T1B, srcC, tgtC, eSrc, eTgt,
        w1_s2t, b1_s2t, w1_t2s, b1_t2s,
        w2pA, b2_s2t, wg_s2t, bg_s2t,
        w2pB, b2_t2s, wg_t2s, bg_t2s,
        wc1p, bc1, wc2, EP, wtBuf, /*dirBase=*/1);
    egnn_node<<<nodeBlocks, 256, 0, stream>>>(NJ, NN, 1);
  }
}

// Round 6
// 320.916 us; speedup vs baseline: 2.6341x; 1.1673x over previous
//
#include <hip/hip_runtime.h>

#define NN 20000
#define NEDGE 320000
#define COORD_MAX 10.0f

#define LDH 136    // ushort stride (272B, 16B-aligned)
#define TILE_N 64
#define LDN  264   // node kernel input stride (K=256)

typedef __attribute__((ext_vector_type(4))) float f32x4;
typedef __attribute__((ext_vector_type(8))) short short8;
typedef __attribute__((ext_vector_type(8))) __bf16 bf16x8;

static __device__ __forceinline__ f32x4 mfma16(short8 a, short8 b, f32x4 c) {
  return __builtin_amdgcn_mfma_f32_16x16x32_bf16(
      __builtin_bit_cast(bf16x8, a), __builtin_bit_cast(bf16x8, b), c, 0, 0, 0);
}
static __device__ __forceinline__ unsigned short f2bf(float f) {
  unsigned u = __builtin_bit_cast(unsigned, f);
  u += 0x7FFFu + ((u >> 16) & 1u);
  return (unsigned short)(u >> 16);
}
static __device__ __forceinline__ float bf2f(unsigned short u) {
  unsigned x = ((unsigned)u) << 16;
  return __builtin_bit_cast(float, x);
}
// packed f32x2 -> bf16x2 (RNE), 1 VALU op (gfx950)
static __device__ __forceinline__ unsigned cvtpk(float lo, float hi) {
  unsigned r;
  asm("v_cvt_pk_bf16_f32 %0, %1, %2" : "=v"(r) : "v"(lo), "v"(hi));
  return r;
}
// fast sigmoid: v_rcp instead of full-precision divide sequence
static __device__ __forceinline__ float sigm(float x) {
  return __builtin_amdgcn_rcpf(1.f + __expf(-x));
}
static __device__ __forceinline__ float silu_(float x) { return x * sigm(x); }

// ---------------------------------------------------------------------------
// Weight pack: fp32 [Kreal][128] row-major -> bf16 MFMA B-fragment order.
// ---------------------------------------------------------------------------
struct PackJobs {
  const float* w[11];
  unsigned short* o[11];
  int kreal[11];
  int nk[11];
};

__global__ void egnn_pack_all(PackJobs J) {
  const int job = blockIdx.y;
  const int nk = J.nk[job];
  const int idx = blockIdx.x * 256 + threadIdx.x;
  if (idx >= nk * 512) return;
  const float* w = J.w[job];
  const int kreal = J.kreal[job];
  const int lane = idx & 63;
  const int ct = (idx >> 6) & 7;
  const int kstep = idx >> 9;
  const int col = ct * 16 + (lane & 15);
  const int k0 = kstep * 32 + (lane >> 4) * 8;
  union { short8 s; unsigned short u[8]; } t;
#pragma unroll
  for (int j = 0; j < 8; ++j) {
    int k = k0 + j;
    t.u[j] = (k < kreal) ? f2bf(w[(size_t)k * 128 + col]) : (unsigned short)0;
  }
  reinterpret_cast<short8*>(J.o[job])[idx] = t.s;
}

// ---------------------------------------------------------------------------
// Precompute S1/T1 = X @ W (K=128), output bf16 [N][128]. 4 jobs via blockIdx.y.
// ---------------------------------------------------------------------------
struct PreJobs {
  const float* x[4];
  const unsigned short* w[4];
  unsigned short* o[4];
};

__global__ __launch_bounds__(256, 2) void egnn_pre(PreJobs J, int N) {
  __shared__ __align__(16) unsigned short sX[64 * LDH];
  const int job = blockIdx.y;
  const float* X = J.x[job];
  const unsigned short* W = J.w[job];
  unsigned short* O = J.o[job];
  const int n0 = blockIdx.x * 64;
  const int tid = threadIdx.x;

  for (int s = tid; s < 64 * 32; s += 256) {
    const int row = s >> 5;
    const int c4 = (s & 31) * 4;
    const int node = n0 + row;
    float4 v = {0.f, 0.f, 0.f, 0.f};
    if (node < N) v = reinterpret_cast<const float4*>(X + (size_t)node * 128)[s & 31];
    *reinterpret_cast<uint2*>(&sX[row * LDH + c4]) =
        uint2{cvtpk(v.x, v.y), cvtpk(v.z, v.w)};
  }
  __syncthreads();

  const int lane = tid & 63, wid = tid >> 6;
  const int r16 = lane & 15, g4 = lane >> 4;
  const int rowBase = wid * 16;

  f32x4 acc[8];
#pragma unroll
  for (int ct = 0; ct < 8; ++ct) acc[ct] = f32x4{0.f, 0.f, 0.f, 0.f};
#pragma unroll
  for (int ks = 0; ks < 4; ++ks) {
    const short8 a = *reinterpret_cast<const short8*>(
        &sX[(rowBase + r16) * LDH + ks * 32 + g4 * 8]);
#pragma unroll
    for (int ct = 0; ct < 8; ++ct) {
      const short8 b = *reinterpret_cast<const short8*>(
          W + ((size_t)(ks * 8 + ct) * 64 + lane) * 8);
      acc[ct] = mfma16(a, b, acc[ct]);
    }
  }
#pragma unroll
  for (int ct = 0; ct < 8; ++ct) {
    const int col = ct * 16 + r16;
#pragma unroll
    for (int r = 0; r < 4; ++r) {
      const int node = n0 + rowBase + g4 * 4 + r;
      if (node < N) O[(size_t)node * 128 + col] = f2bf(acc[ct][r]);
    }
  }
}

// ---------------------------------------------------------------------------
// Counting sort by tgt and by src.
// ---------------------------------------------------------------------------
__global__ void egnn_hist(const int* __restrict__ eTgt, const int* __restrict__ eSrc,
                          int* __restrict__ cntT, int* __restrict__ cntS) {
  const int e = blockIdx.x * 256 + threadIdx.x;
  if (e < NEDGE) {
    atomicAdd(&cntT[eTgt[e]], 1);
    atomicAdd(&cntS[eSrc[e]], 1);
  }
}

__global__ __launch_bounds__(1024) void egnn_scan(
    const int* __restrict__ c0, int* __restrict__ r0, int* __restrict__ o0,
    const int* __restrict__ c1, int* __restrict__ r1, int* __restrict__ o1, int n) {
  const int* cnt = blockIdx.x ? c1 : c0;
  int* rp = blockIdx.x ? r1 : r0;
  int* oc = blockIdx.x ? o1 : o0;
  __shared__ int sums[1024];
  const int tid = threadIdx.x;
  const int chunk = (n + 1023) / 1024;
  const int i0 = tid * chunk;
  int local = 0;
  for (int k = 0; k < chunk; ++k) {
    const int i = i0 + k;
    if (i < n) local += cnt[i];
  }
  sums[tid] = local;
  __syncthreads();
  for (int s = 1; s < 1024; s <<= 1) {
    int v = (tid >= s) ? sums[tid - s] : 0;
    __syncthreads();
    sums[tid] += v;
    __syncthreads();
  }
  int run = (tid == 0) ? 0 : sums[tid - 1];
  for (int k = 0; k < chunk; ++k) {
    const int i = i0 + k;
    if (i < n) { rp[i] = run; oc[i] = run; run += cnt[i]; }
  }
  if (tid == 1023) rp[n] = sums[1023];
}

__global__ void egnn_scatter(const int* __restrict__ eTgt, const int* __restrict__ eSrc,
                             int* __restrict__ offT, int* __restrict__ offS,
                             int* __restrict__ permT, int* __restrict__ permS) {
  const int e = blockIdx.x * 256 + threadIdx.x;
  if (e < NEDGE) {
    permT[atomicAdd(&offT[eTgt[e]], 1)] = e;
    permS[atomicAdd(&offS[eSrc[e]], 1)] = e;
  }
}

// ---------------------------------------------------------------------------
// Fused edge kernel, sorted order. 128 edges/block, 4 waves x 32 edges,
// dir = blockIdx.y. Segmented reduction straight into agg (no eBuf):
// wave-interior node segments -> plain store; boundary segments -> atomicAdd.
// dir0 additionally: coord MLP -> wtBuf at sorted position.
// ---------------------------------------------------------------------------
__global__ __launch_bounds__(256, 4) void egnn_edge(
    const unsigned short* __restrict__ S1A, const unsigned short* __restrict__ T1A,
    const unsigned short* __restrict__ S1B, const unsigned short* __restrict__ T1B,
    const float* __restrict__ srcC, const float* __restrict__ tgtC,
    const int* __restrict__ eSrc, const int* __restrict__ eTgt,
    const float* __restrict__ w1A, const float* __restrict__ b1A,
    const float* __restrict__ w1B, const float* __restrict__ b1B,
    const unsigned short* __restrict__ w2pA, const float* __restrict__ b2A,
    const float* __restrict__ wgA, const float* __restrict__ bgA,
    const unsigned short* __restrict__ w2pB, const float* __restrict__ b2B,
    const float* __restrict__ wgB, const float* __restrict__ bgB,
    const unsigned short* __restrict__ wc1p, const float* __restrict__ bc1,
    const float* __restrict__ wc2,
    const int* __restrict__ permT, const int* __restrict__ permS,
    float* __restrict__ aggA, float* __restrict__ aggB,
    float* __restrict__ wtBuf)
{
  __shared__ __align__(16) unsigned short sH[4][32 * LDH];  // 34816 B
  __shared__ float sCD[128 * 3];
  __shared__ float sRad[128];
  __shared__ int sS[128];
  __shared__ int sT[128];

  const int dir = blockIdx.y;
  const int tid = threadIdx.x;
  const int j0 = blockIdx.x * 128;
  const int* __restrict__ perm = dir ? permS : permT;

  if (tid < 128) {
    const int e = perm[j0 + tid];
    const int s = eSrc[e], t = eTgt[e];
    sS[tid] = s; sT[tid] = t;
    const float dx = tgtC[t * 3 + 0] - srcC[s * 3 + 0];
    const float dy = tgtC[t * 3 + 1] - srcC[s * 3 + 1];
    const float dz = tgtC[t * 3 + 2] - srcC[s * 3 + 2];
    sCD[tid * 3 + 0] = dx; sCD[tid * 3 + 1] = dy; sCD[tid * 3 + 2] = dz;
    sRad[tid] = dx * dx + dy * dy + dz * dz;
  }
  __syncthreads();

  const int lane = tid & 63, wid = tid >> 6;
  const int r16 = lane & 15, g4 = lane >> 4;
  const int we = wid * 32;
  const int h32 = lane >> 5;
  const int c4 = (lane & 31) * 4;

  const unsigned short* S1 = dir ? S1B : S1A;
  const unsigned short* T1 = dir ? T1B : T1A;
  const float* w1 = dir ? w1B : w1A;
  const float* b1 = dir ? b1B : b1A;
  const float4 wr = *reinterpret_cast<const float4*>(w1 + 256 * 128 + c4);
  const float4 bb = *reinterpret_cast<const float4*>(b1 + c4);

  unsigned short* hT = sH[wid];

  // ---- build h-tile: h = silu(S1[s] + T1[t] + rad*wr + bb), bf16 -> LDS
#pragma unroll 8
  for (int i = 0; i < 16; ++i) {
    const int row = 2 * i + h32;
    const int e = we + row;
    const int s = sS[e], t = sT[e];
    const float rad = sRad[e];
    const ushort4 a = *reinterpret_cast<const ushort4*>(S1 + (size_t)s * 128 + c4);
    const ushort4 b = *reinterpret_cast<const ushort4*>(T1 + (size_t)t * 128 + c4);
    const float f0 = silu_(bf2f(a.x) + bf2f(b.x) + rad * wr.x + bb.x);
    const float f1 = silu_(bf2f(a.y) + bf2f(b.y) + rad * wr.y + bb.y);
    const float f2 = silu_(bf2f(a.z) + bf2f(b.z) + rad * wr.z + bb.z);
    const float f3 = silu_(bf2f(a.w) + bf2f(b.w) + rad * wr.w + bb.w);
    *reinterpret_cast<uint2*>(&hT[row * LDH + c4]) =
        uint2{cvtpk(f0, f1), cvtpk(f2, f3)};
  }

  // ---- GEMM2: 2 row-tiles x [16x128] @ [128x128]
  const unsigned short* w2p = dir ? w2pB : w2pA;
  f32x4 acc[2][8];
#pragma unroll
  for (int rt = 0; rt < 2; ++rt)
#pragma unroll
    for (int ct = 0; ct < 8; ++ct) acc[rt][ct] = f32x4{0.f, 0.f, 0.f, 0.f};
#pragma unroll
  for (int ks = 0; ks < 4; ++ks) {
    short8 a[2];
#pragma unroll
    for (int rt = 0; rt < 2; ++rt)
      a[rt] = *reinterpret_cast<const short8*>(
          &hT[(rt * 16 + r16) * LDH + ks * 32 + g4 * 8]);
#pragma unroll
    for (int ct = 0; ct < 8; ++ct) {
      const short8 b = *reinterpret_cast<const short8*>(
          w2p + ((size_t)(ks * 8 + ct) * 64 + lane) * 8);
#pragma unroll
      for (int rt = 0; rt < 2; ++rt) acc[rt][ct] = mfma16(a[rt], b, acc[rt][ct]);
    }
  }

  // ---- bias + SiLU + gate
  const float* b2 = dir ? b2B : b2A;
  const float* wg = dir ? wgB : wgA;
  const float bg = dir ? bgB[0] : bgA[0];
  float part[2][4];
#pragma unroll
  for (int rt = 0; rt < 2; ++rt)
#pragma unroll
    for (int r = 0; r < 4; ++r) part[rt][r] = 0.f;
#pragma unroll
  for (int ct = 0; ct < 8; ++ct) {
    const float b2v = b2[ct * 16 + r16];
    const float wgv = wg[ct * 16 + r16];
#pragma unroll
    for (int rt = 0; rt < 2; ++rt)
#pragma unroll
      for (int r = 0; r < 4; ++r) {
        const float e = silu_(acc[rt][ct][r] + b2v);
        acc[rt][ct][r] = e;
        part[rt][r] += e * wgv;
      }
  }
#pragma unroll
  for (int m = 1; m < 16; m <<= 1)
#pragma unroll
    for (int rt = 0; rt < 2; ++rt)
#pragma unroll
      for (int r = 0; r < 4; ++r) part[rt][r] += __shfl_xor(part[rt][r], m, 64);
#pragma unroll
  for (int rt = 0; rt < 2; ++rt)
#pragma unroll
    for (int r = 0; r < 4; ++r) {
      const float gate = sigm(part[rt][r] + bg);
#pragma unroll
      for (int ct = 0; ct < 8; ++ct) acc[rt][ct][r] *= gate;
    }

  // ---- stash gated e (bf16) into LDS (transpose: row = edge, col = feature)
#pragma unroll
  for (int rt = 0; rt < 2; ++rt)
#pragma unroll
    for (int ct = 0; ct < 8; ++ct)
#pragma unroll
      for (int r = 0; r < 4; ++r)
        hT[(rt * 16 + g4 * 4 + r) * LDH + ct * 16 + r16] = f2bf(acc[rt][ct][r]);

  if (dir == 0) {
    // ---- coord GEMM on gated e_s2t
    f32x4 ac[2][8];
#pragma unroll
    for (int rt = 0; rt < 2; ++rt)
#pragma unroll
      for (int ct = 0; ct < 8; ++ct) ac[rt][ct] = f32x4{0.f, 0.f, 0.f, 0.f};
#pragma unroll
    for (int ks = 0; ks < 4; ++ks) {
      short8 a[2];
#pragma unroll
      for (int rt = 0; rt < 2; ++rt)
        a[rt] = *reinterpret_cast<const short8*>(
            &hT[(rt * 16 + r16) * LDH + ks * 32 + g4 * 8]);
#pragma unroll
      for (int ct = 0; ct < 8; ++ct) {
        const short8 b = *reinterpret_cast<const short8*>(
            wc1p + ((size_t)(ks * 8 + ct) * 64 + lane) * 8);
#pragma unroll
        for (int rt = 0; rt < 2; ++rt) ac[rt][ct] = mfma16(a[rt], b, ac[rt][ct]);
      }
    }
    float pc[2][4];
#pragma unroll
    for (int rt = 0; rt < 2; ++rt)
#pragma unroll
      for (int r = 0; r < 4; ++r) pc[rt][r] = 0.f;
#pragma unroll
    for (int ct = 0; ct < 8; ++ct) {
      const float bcv = bc1[ct * 16 + r16];
      const float w2v = wc2[ct * 16 + r16];
#pragma unroll
      for (int rt = 0; rt < 2; ++rt)
#pragma unroll
        for (int r = 0; r < 4; ++r)
          pc[rt][r] += silu_(ac[rt][ct][r] + bcv) * w2v;
    }
#pragma unroll
    for (int m = 1; m < 16; m <<= 1)
#pragma unroll
      for (int rt = 0; rt < 2; ++rt)
#pragma unroll
        for (int r = 0; r < 4; ++r) pc[rt][r] += __shfl_xor(pc[rt][r], m, 64);

    // per-edge weighted coord diff -> wtBuf (sorted position), no atomics
#pragma unroll
    for (int rt = 0; rt < 2; ++rt)
#pragma unroll
      for (int r = 0; r < 4; ++r) {
        if (r16 == 0) {
          const int el = we + rt * 16 + g4 * 4 + r;
          const float p = pc[rt][r];
          const float4 w = {sCD[el * 3 + 0] * p, sCD[el * 3 + 1] * p,
                            sCD[el * 3 + 2] * p, 0.f};
          *reinterpret_cast<float4*>(wtBuf + (size_t)(j0 + el) * 4) = w;
        }
      }
  }

  // ---- segmented reduction of this wave's 32 gated-e rows into agg.
  // Sorted order => each node's rows are contiguous. Node ids wave-uniform.
  // Interior segment (starts after row 0 AND ends before row 31): this node's
  // edges are provably all inside this wave -> exclusive plain store.
  // Boundary segment: may continue in neighbor wave/block -> atomicAdd.
  {
    const int* __restrict__ nids = dir ? sS : sT;
    float* __restrict__ agg = dir ? aggB : aggA;
    const int c2 = lane * 2;
    float s0 = 0.f, s1 = 0.f;
    int curNode = nids[we];
    int segStart = 0;
#pragma unroll 4
    for (int row = 0; row < 32; ++row) {
      const ushort2 v = *reinterpret_cast<const ushort2*>(&hT[row * LDH + c2]);
      s0 += bf2f(v.x); s1 += bf2f(v.y);
      const int nxt = (row < 31) ? nids[we + row + 1] : -1;
      if (nxt != curNode) {
        float* dst = agg + (size_t)curNode * 128 + c2;
        if (segStart > 0 && row < 31) {
          dst[0] = s0; dst[1] = s1;
        } else {
          atomicAdd(dst, s0);
          atomicAdd(dst + 1, s1);
        }
        s0 = 0.f; s1 = 0.f;
        curNode = nxt; segStart = row + 1;
      }
    }
  }
}

// ---------------------------------------------------------------------------
// Coord finalize: segmented sum of wtBuf by tgt (contiguous), /max(deg,1),
// clip, add; also copy src coords.
// ---------------------------------------------------------------------------
__global__ void egnn_coord(const float* __restrict__ srcC, const float* __restrict__ tgtC,
                           const float* __restrict__ wt, const int* __restrict__ rp,
                           float* __restrict__ outSC, float* __restrict__ outTC) {
  const int n = blockIdx.x * 256 + threadIdx.x;
  if (n >= NN) return;
  outSC[n * 3 + 0] = srcC[n * 3 + 0];
  outSC[n * 3 + 1] = srcC[n * 3 + 1];
  outSC[n * 3 + 2] = srcC[n * 3 + 2];
  const int j0 = rp[n], j1 = rp[n + 1];
  float ax = 0.f, ay = 0.f, az = 0.f;
  for (int j = j0; j < j1; ++j) {
    const float4 v = *reinterpret_cast<const float4*>(wt + (size_t)j * 4);
    ax += v.x; ay += v.y; az += v.z;
  }
  const float c = fmaxf((float)(j1 - j0), 1.f);
  ax = fminf(fmaxf(ax / c, -COORD_MAX), COORD_MAX);
  ay = fminf(fmaxf(ay / c, -COORD_MAX), COORD_MAX);
  az = fminf(fmaxf(az / c, -COORD_MAX), COORD_MAX);
  outTC[n * 3 + 0] = tgtC[n * 3 + 0] + ax;
  outTC[n * 3 + 1] = tgtC[n * 3 + 1] + ay;
  outTC[n * 3 + 2] = tgtC[n * 3 + 2] + az;
}

// ---------------------------------------------------------------------------
// Node kernel: out = feat + (silu([feat|agg] @ wn1 + bn1) @ wn2 + bn2)
// agg is fp32 (pre-reduced by edge kernel). 2 jobs via grid.y.
// ---------------------------------------------------------------------------
struct NodeJobs {
  const float* feat[2];
  const float* agg[2];
  const unsigned short* w1p[2];
  const float* b1[2];
  const unsigned short* w2p[2];
  const float* b2[2];
  float* outp[2];
};

__global__ __launch_bounds__(256, 2) void egnn_node(NodeJobs J, int N) {
  __shared__ __align__(16) unsigned short sIn[TILE_N * LDN];
  __shared__ __align__(16) unsigned short sH2[TILE_N * LDH];
  const int job = blockIdx.y;
  const float* __restrict__ feat = J.feat[job];
  const float* __restrict__ agg = J.agg[job];
  const unsigned short* __restrict__ w1p = J.w1p[job];
  const float* __restrict__ b1 = J.b1[job];
  const unsigned short* __restrict__ w2p = J.w2p[job];
  const float* __restrict__ b2 = J.b2[job];
  float* __restrict__ outp = J.outp[job];

  const int tid = threadIdx.x;
  const int n0 = blockIdx.x * TILE_N;

  // ---- stage [feat | agg] (bf16), 256 cols
  for (int s = tid; s < 64 * 64; s += 256) {
    const int row = s >> 6;
    const int half = (s >> 5) & 1;          // 0 = feat, 1 = agg
    const int c4 = (s & 31) * 4;
    const int node = n0 + row;
    float4 v = {0.f, 0.f, 0.f, 0.f};
    if (node < N)
      v = reinterpret_cast<const float4*>((half ? agg : feat) + (size_t)node * 128)[s & 31];
    *reinterpret_cast<uint2*>(&sIn[row * LDN + half * 128 + c4]) =
        uint2{cvtpk(v.x, v.y), cvtpk(v.z, v.w)};
  }
  __syncthreads();

  const int lane = tid & 63;
  const int wid = tid >> 6;
  const int rowBase = wid * 16;
  const int r16 = lane & 15;
  const int g4 = lane >> 4;

  f32x4 acc[8];
#pragma unroll
  for (int ct = 0; ct < 8; ++ct) acc[ct] = f32x4{0.f, 0.f, 0.f, 0.f};
#pragma unroll
  for (int ks = 0; ks < 8; ++ks) {
    const short8 a = *reinterpret_cast<const short8*>(
        &sIn[(rowBase + r16) * LDN + ks * 32 + g4 * 8]);
#pragma unroll
    for (int ct = 0; ct < 8; ++ct) {
      const short8 b = *reinterpret_cast<const short8*>(
          w1p + ((size_t)(ks * 8 + ct) * 64 + lane) * 8);
      acc[ct] = mfma16(a, b, acc[ct]);
    }
  }
#pragma unroll
  for (int ct = 0; ct < 8; ++ct) {
    const int col = ct * 16 + r16;
    const float bias = b1[col];
#pragma unroll
    for (int r = 0; r < 4; ++r) {
      const float h = silu_(acc[ct][r] + bias);
      sH2[(rowBase + g4 * 4 + r) * LDH + col] = f2bf(h);
    }
  }

  f32x4 acc2[8];
#pragma unroll
  for (int ct = 0; ct < 8; ++ct) acc2[ct] = f32x4{0.f, 0.f, 0.f, 0.f};
#pragma unroll
  for (int ks = 0; ks < 4; ++ks) {
    const short8 a = *reinterpret_cast<const short8*>(
        &sH2[(rowBase + r16) * LDH + ks * 32 + g4 * 8]);
#pragma unroll
    for (int ct = 0; ct < 8; ++ct) {
      const short8 b = *reinterpret_cast<const short8*>(
          w2p + ((size_t)(ks * 8 + ct) * 64 + lane) * 8);
      acc2[ct] = mfma16(a, b, acc2[ct]);
    }
  }

#pragma unroll
  for (int ct = 0; ct < 8; ++ct) {
    const int col = ct * 16 + r16;
    const float bias = b2[col];
#pragma unroll
    for (int r = 0; r < 4; ++r) {
      const int node = n0 + rowBase + g4 * 4 + r;
      if (node < N)
        outp[(size_t)node * 128 + col] = feat[(size_t)node * 128 + col] + acc2[ct][r] + bias;
    }
  }
}

extern "C" void kernel_launch(void* const* d_in, const int* in_sizes, int n_in,
                              void* d_out, int out_size, void* d_ws, size_t ws_size,
                              hipStream_t stream) {
  const float* srcF = (const float*)d_in[0];
  const float* tgtF = (const float*)d_in[1];
  const float* srcC = (const float*)d_in[2];
  const float* tgtC = (const float*)d_in[3];
  const int* eSrc = (const int*)d_in[4];
  const int* eTgt = (const int*)d_in[5];
  const float* w1_s2t = (const float*)d_in[6];
  const float* b1_s2t = (const float*)d_in[7];
  const float* w2_s2t = (const float*)d_in[8];
  const float* b2_s2t = (const float*)d_in[9];
  const float* w1_t2s = (const float*)d_in[10];
  const float* b1_t2s = (const float*)d_in[11];
  const float* w2_t2s = (const float*)d_in[12];
  const float* b2_t2s = (const float*)d_in[13];
  const float* wg_s2t = (const float*)d_in[14];
  const float* bg_s2t = (const float*)d_in[15];
  const float* wg_t2s = (const float*)d_in[16];
  const float* bg_t2s = (const float*)d_in[17];
  const float* wc1 = (const float*)d_in[18];
  const float* bc1 = (const float*)d_in[19];
  const float* wc2 = (const float*)d_in[20];
  const float* wn1_t = (const float*)d_in[21];
  const float* bn1_t = (const float*)d_in[22];
  const float* wn2_t = (const float*)d_in[23];
  const float* bn2_t = (const float*)d_in[24];
  const float* wn1_s = (const float*)d_in[25];
  const float* bn1_s = (const float*)d_in[26];
  const float* wn2_s = (const float*)d_in[27];
  const float* bn2_s = (const float*)d_in[28];

  char* ws = (char*)d_ws;
  size_t off = 0;
  auto take = [&](size_t bytes) -> char* {
    char* p = ws + off;
    off = (off + bytes + 255) & ~(size_t)255;
    return p;
  };
  float* aggA = (float*)take((size_t)NN * 128 * 4);   // 10.24 MB (zeroed)
  float* aggB = (float*)take((size_t)NN * 128 * 4);   // 10.24 MB (zeroed, contiguous)
  float* wtBuf = (float*)take((size_t)NEDGE * 4 * 4); // 5.12 MB
  unsigned short* S1A = (unsigned short*)take((size_t)NN * 128 * 2);
  unsigned short* T1A = (unsigned short*)take((size_t)NN * 128 * 2);
  unsigned short* S1B = (unsigned short*)take((size_t)NN * 128 * 2);
  unsigned short* T1B = (unsigned short*)take((size_t)NN * 128 * 2);
  unsigned short* w1tA = (unsigned short*)take(4 * 4096 * 2);
  unsigned short* w1mA = (unsigned short*)take(4 * 4096 * 2);
  unsigned short* w1tB = (unsigned short*)take(4 * 4096 * 2);
  unsigned short* w1mB = (unsigned short*)take(4 * 4096 * 2);
  unsigned short* w2pA = (unsigned short*)take(4 * 4096 * 2);
  unsigned short* w2pB = (unsigned short*)take(4 * 4096 * 2);
  unsigned short* wc1p = (unsigned short*)take(4 * 4096 * 2);
  unsigned short* wn1pt = (unsigned short*)take(8 * 4096 * 2);
  unsigned short* wn2pt = (unsigned short*)take(4 * 4096 * 2);
  unsigned short* wn1ps = (unsigned short*)take(8 * 4096 * 2);
  unsigned short* wn2ps = (unsigned short*)take(4 * 4096 * 2);
  int* cntT = (int*)take((size_t)NN * 4);
  int* cntS = (int*)take((size_t)NN * 4);
  const char* cntZeroStart = (const char*)cntT;
  const size_t cntZeroBytes = (size_t)((char*)cntS + NN * 4 - (char*)cntT);
  int* rowptrT = (int*)take((size_t)(NN + 1) * 4);
  int* rowptrS = (int*)take((size_t)(NN + 1) * 4);
  int* offT = (int*)take((size_t)NN * 4);
  int* offS = (int*)take((size_t)NN * 4);
  int* permT = (int*)take((size_t)NEDGE * 4);
  int* permS = (int*)take((size_t)NEDGE * 4);

  // zero agg accumulators (boundary segments use atomicAdd) and hist counters
  hipMemsetAsync(aggA, 0, (size_t)NN * 128 * 4 * 2, stream);
  hipMemsetAsync((void*)cntZeroStart, 0, cntZeroBytes, stream);

  PackJobs PJ;
  PJ.w[0] = w1_s2t;             PJ.o[0] = w1tA;  PJ.kreal[0] = 128; PJ.nk[0] = 4;
  PJ.w[1] = w1_s2t + 128 * 128; PJ.o[1] = w1mA;  PJ.kreal[1] = 128; PJ.nk[1] = 4;
  PJ.w[2] = w1_t2s;             PJ.o[2] = w1tB;  PJ.kreal[2] = 128; PJ.nk[2] = 4;
  PJ.w[3] = w1_t2s + 128 * 128; PJ.o[3] = w1mB;  PJ.kreal[3] = 128; PJ.nk[3] = 4;
  PJ.w[4] = w2_s2t;             PJ.o[4] = w2pA;  PJ.kreal[4] = 128; PJ.nk[4] = 4;
  PJ.w[5] = w2_t2s;             PJ.o[5] = w2pB;  PJ.kreal[5] = 128; PJ.nk[5] = 4;
  PJ.w[6] = wc1;                PJ.o[6] = wc1p;  PJ.kreal[6] = 128; PJ.nk[6] = 4;
  PJ.w[7] = wn1_t;              PJ.o[7] = wn1pt; PJ.kreal[7] = 256; PJ.nk[7] = 8;
  PJ.w[8] = wn2_t;              PJ.o[8] = wn2pt; PJ.kreal[8] = 128; PJ.nk[8] = 4;
  PJ.w[9] = wn1_s;              PJ.o[9] = wn1ps; PJ.kreal[9] = 256; PJ.nk[9] = 8;
  PJ.w[10] = wn2_s;             PJ.o[10] = wn2ps; PJ.kreal[10] = 128; PJ.nk[10] = 4;
  egnn_pack_all<<<dim3(16, 11), 256, 0, stream>>>(PJ);

  PreJobs PR;
  PR.x[0] = srcF; PR.w[0] = w1tA; PR.o[0] = S1A;
  PR.x[1] = tgtF; PR.w[1] = w1mA; PR.o[1] = T1A;
  PR.x[2] = srcF; PR.w[2] = w1tB; PR.o[2] = S1B;
  PR.x[3] = tgtF; PR.w[3] = w1mB; PR.o[3] = T1B;
  egnn_pre<<<dim3(313, 4), 256, 0, stream>>>(PR, NN);

  egnn_hist<<<NEDGE / 256, 256, 0, stream>>>(eTgt, eSrc, cntT, cntS);
  egnn_scan<<<2, 1024, 0, stream>>>(cntT, rowptrT, offT, cntS, rowptrS, offS, NN);
  egnn_scatter<<<NEDGE / 256, 256, 0, stream>>>(eTgt, eSrc, offT, offS, permT, permS);

  float* outSrc = (float*)d_out;
  float* outTgt = outSrc + (size_t)NN * 128;
  float* outSC  = outTgt + (size_t)NN * 128;
  float* outTC  = outSC + (size_t)NN * 3;

  egnn_edge<<<dim3(NEDGE / 128, 2), 256, 0, stream>>>(
      S1A, T1A, S1B, T1B, srcC, tgtC, eSrc, eTgt,
      w1_s2t, b1_s2t, w1_t2s, b1_t2s,
      w2pA, b2_s2t, wg_s2t, bg_s2t,
      w2pB, b2_t2s, wg_t2s, bg_t2s,
      wc1p, bc1, wc2, permT, permS, aggA, aggB, wtBuf);

  egnn_coord<<<(NN + 255) / 256, 256, 0, stream>>>(
      srcC, tgtC, wtBuf, rowptrT, outSC, outTC);

  NodeJobs NJ;
  NJ.feat[0] = tgtF; NJ.agg[0] = aggA;
  NJ.w1p[0] = wn1pt; NJ.b1[0] = bn1_t; NJ.w2p[0] = wn2pt; NJ.b2[0] = bn2_t;
  NJ.outp[0] = outTgt;
  NJ.feat[1] = srcF; NJ.agg[1] = aggB;
  NJ.w1p[1] = wn1ps; NJ.b1[1] = bn1_s; NJ.w2p[1] = wn2ps; NJ.b2[1] = bn2_s;
  NJ.outp[1] = outSrc;

  const int nodeBlocks = (NN + TILE_N - 1) / TILE_N;
  egnn_node<<<dim3(nodeBlocks, 2), 256, 0, stream>>>(NJ, NN);
}